// Round 4
// baseline (15432.298 us; speedup 1.0000x reference)
//
#include <hip/hip_runtime.h>
#include <hip/hip_cooperative_groups.h>

namespace cg = cooperative_groups;

// Problem dims (hardcoded per reference)
constexpr int kB   = 64;    // batch
constexpr int kM   = 32;    // rows
constexpr int kN   = 32;    // cols
constexpr int kD   = 256;   // input/vocab dim
constexpr int kH   = 256;   // hidden
constexpr int kG5  = 1280;  // 5H

typedef __attribute__((ext_vector_type(8)))  short bf16x8;
typedef __attribute__((ext_vector_type(16))) float f32x16;

__device__ __forceinline__ float bu2f(unsigned short u) {
    return __uint_as_float(((unsigned)u) << 16);
}
__device__ __forceinline__ unsigned short f2bu(float f) {
    unsigned u = __float_as_uint(f);
    return (unsigned short)((u + 0x7FFF + ((u >> 16) & 1)) >> 16);   // RNE
}
__device__ __forceinline__ void split1(float a, unsigned short& hi, unsigned short& lo) {
    hi = f2bu(a);
    lo = f2bu(a - bu2f(hi));     // |residual after lo| <= 2^-18 |a|
}
__device__ __forceinline__ float sigm(float x) { return 1.f / (1.f + expf(-x)); }

// ---------------------------------------------------------------------------
// Prep 1: swizzle Wg (fp32 [768][1280]) into MFMA-B-fragment-contiguous bf16
// hi/lo panels. B-frag for v_mfma_f32_32x32x16_bf16: lane l holds
// B[k=(l>>5)*8+j][n=l&31]. 40 ntiles x 48 chunks.
// ---------------------------------------------------------------------------
__global__ void prep_w(const float* __restrict__ Wg,
                       unsigned short* __restrict__ whi,
                       unsigned short* __restrict__ wlo) {
    const int t = blockIdx.x * 256 + threadIdx.x;     // 0..122879
    const int lane = t & 63;
    const int rest = t >> 6;
    const int s = rest % 48;
    const int ntile = rest / 48;
    const int n = ntile * 32 + (lane & 31);
    const int kb = s * 16 + (lane >> 5) * 8;
    unsigned short h8[8], l8[8];
    #pragma unroll
    for (int j = 0; j < 8; ++j) {
        const float a = Wg[(size_t)(kb + j) * kG5 + n];
        split1(a, h8[j], l8[j]);
    }
    *(bf16x8*)(whi + (size_t)t * 8) = *(const bf16x8*)h8;
    *(bf16x8*)(wlo + (size_t)t * 8) = *(const bf16x8*)l8;
}

// Prep 2: W_head (fp32 [256][256]) -> B-frag bf16 hi/lo (8 ntiles x 16 chunks)
__global__ void prep_wh(const float* __restrict__ Wh,
                        unsigned short* __restrict__ whh,
                        unsigned short* __restrict__ whl) {
    const int t = blockIdx.x * 256 + threadIdx.x;     // 0..8191
    const int lane = t & 63;
    const int rest = t >> 6;                          // 0..127
    const int kc = rest & 15;
    const int nt = rest >> 4;                         // 0..7
    const int n = nt * 32 + (lane & 31);
    const int kb = kc * 16 + (lane >> 5) * 8;
    unsigned short h8[8], l8[8];
    #pragma unroll
    for (int j = 0; j < 8; ++j) {
        const float a = Wh[(size_t)(kb + j) * kD + n];
        split1(a, h8[j], l8[j]);
    }
    *(bf16x8*)(whh + (size_t)t * 8) = *(const bf16x8*)h8;
    *(bf16x8*)(whl + (size_t)t * 8) = *(const bf16x8*)l8;
}

// Prep 3: h_init -> A-frag layout [kh 0..15][lane][8]
__global__ void prep_h0f(const float* __restrict__ hinit,
                         unsigned short* __restrict__ h0fh,
                         unsigned short* __restrict__ h0fl) {
    const int idx = blockIdx.x * 256 + threadIdx.x;   // 0..1023
    const int lane = idx & 63;
    const int kh = idx >> 6;
    const int k0 = kh * 16 + (lane >> 5) * 8;
    unsigned short h8[8], l8[8];
    #pragma unroll
    for (int j = 0; j < 8; ++j) split1(hinit[k0 + j], h8[j], l8[j]);
    *(bf16x8*)(h0fh + (size_t)idx * 8) = *(const bf16x8*)h8;
    *(bf16x8*)(h0fl + (size_t)idx * 8) = *(const bf16x8*)l8;
}

// ---------------------------------------------------------------------------
// Prep 4: pre-split ALL of x into A-frag bf16 hi/lo panels.
// Per (cell,mt): [kh 0..15][lane 0..63][8].
// ---------------------------------------------------------------------------
__global__ void prep_x(const float* __restrict__ x,
                       unsigned short* __restrict__ xfh,
                       unsigned short* __restrict__ xfl) {
    const int t = blockIdx.x * 256 + threadIdx.x;     // 0..2097151
    const int kq   = t & 31;            // k/8
    const int b    = (t >> 5) & 63;
    const int cell = t >> 11;           // i*kN+j, 0..1023
    const float* src = x + (((size_t)b * 1024 + cell) * kD + kq * 8);
    unsigned short h8[8], l8[8];
    #pragma unroll
    for (int j = 0; j < 8; ++j) split1(src[j], h8[j], l8[j]);
    const int mt = b >> 5, kh = kq >> 1;
    const int l  = (b & 31) + 32 * (kq & 1);
    const size_t dst = ((((size_t)cell * 2 + mt) * 16 + kh) * 64 + l) * 8;
    *(bf16x8*)(xfh + dst) = *(const bf16x8*)h8;
    *(bf16x8*)(xfl + dst) = *(const bf16x8*)l8;
}

// ---------------------------------------------------------------------------
// Gate unit body (verified in round 3): unit = cell*20 + nc. Wave = 1 m-tile
// x 1 n-tile, 144 MFMA, barrier-free, all A operands pre-swizzled.
// ---------------------------------------------------------------------------
__device__ __forceinline__
void gate_unit_body(int d, int unit,
                    const unsigned short* __restrict__ xfh,
                    const unsigned short* __restrict__ xfl,
                    const unsigned short* __restrict__ whi,
                    const unsigned short* __restrict__ wlo,
                    const unsigned short* __restrict__ hfh,
                    const unsigned short* __restrict__ hfl,
                    const unsigned short* __restrict__ h0fh,
                    const unsigned short* __restrict__ h0fl,
                    float* __restrict__ gates) {
    const int tid = threadIdx.x;
    const int ilo = max(0, d - (kN - 1));
    const int cell = unit / 20;
    const int nc   = unit % 20;
    const int i = ilo + cell;
    const int j = d - i;
    const int w = tid >> 6, lane = tid & 63;
    const int ln31 = lane & 31, ln5 = lane >> 5;
    const int mt = w & 1;                        // m-tile (batch rows mt*32..)
    const int ntile = nc * 2 + (w >> 1);         // global 32-col tile
    const int hp = (d + 1) & 1;                  // h plane written at diag d-1
    const int cl = i * kN + j;                   // linear cell index

    f32x16 acc;
    #pragma unroll
    for (int r = 0; r < 16; ++r) acc[r] = 0.f;

    const unsigned short* wph = whi + ((size_t)ntile * 3072 + lane) * 8;
    const unsigned short* wpl = wlo + ((size_t)ntile * 3072 + lane) * 8;

    // ---- x part: chunks 0..15, pre-split frags ----
    const unsigned short* xph = xfh + (((size_t)cl * 2 + mt) * 16 * 64 + lane) * 8;
    const unsigned short* xpl = xfl + (((size_t)cl * 2 + mt) * 16 * 64 + lane) * 8;
    #pragma unroll 4
    for (int kh = 0; kh < 16; ++kh) {
        const bf16x8 ah = *(const bf16x8*)(xph + (size_t)kh * 512);
        const bf16x8 al = *(const bf16x8*)(xpl + (size_t)kh * 512);
        const bf16x8 wh = *(const bf16x8*)(wph + (size_t)kh * 512);
        const bf16x8 wl = *(const bf16x8*)(wpl + (size_t)kh * 512);
        acc = __builtin_amdgcn_mfma_f32_32x32x16_bf16(ah, wh, acc, 0, 0, 0);
        acc = __builtin_amdgcn_mfma_f32_32x32x16_bf16(ah, wl, acc, 0, 0, 0);
        acc = __builtin_amdgcn_mfma_f32_32x32x16_bf16(al, wh, acc, 0, 0, 0);
    }

    // ---- h_l part: chunks 16..31; h_u part: chunks 32..47 ----
    const unsigned short *plh, *pll, *puh, *pul;
    if (j > 0) {
        const size_t o = ((size_t)(hp * kM + i)) * 16384 + ((size_t)(mt * 16) * 64 + lane) * 8;
        plh = hfh + o; pll = hfl + o;
    } else {
        plh = h0fh + lane * 8; pll = h0fl + lane * 8;
    }
    if (i > 0) {
        const size_t o = ((size_t)(hp * kM + (i - 1))) * 16384 + ((size_t)(mt * 16) * 64 + lane) * 8;
        puh = hfh + o; pul = hfl + o;
    } else {
        puh = h0fh + lane * 8; pul = h0fl + lane * 8;
    }

    #pragma unroll 4
    for (int kh = 0; kh < 16; ++kh) {
        const bf16x8 ah = *(const bf16x8*)(plh + (size_t)kh * 512);
        const bf16x8 al = *(const bf16x8*)(pll + (size_t)kh * 512);
        const bf16x8 wh = *(const bf16x8*)(wph + (size_t)(16 + kh) * 512);
        const bf16x8 wl = *(const bf16x8*)(wpl + (size_t)(16 + kh) * 512);
        acc = __builtin_amdgcn_mfma_f32_32x32x16_bf16(ah, wh, acc, 0, 0, 0);
        acc = __builtin_amdgcn_mfma_f32_32x32x16_bf16(ah, wl, acc, 0, 0, 0);
        acc = __builtin_amdgcn_mfma_f32_32x32x16_bf16(al, wh, acc, 0, 0, 0);
    }
    #pragma unroll 4
    for (int kh = 0; kh < 16; ++kh) {
        const bf16x8 ah = *(const bf16x8*)(puh + (size_t)kh * 512);
        const bf16x8 al = *(const bf16x8*)(pul + (size_t)kh * 512);
        const bf16x8 wh = *(const bf16x8*)(wph + (size_t)(32 + kh) * 512);
        const bf16x8 wl = *(const bf16x8*)(wpl + (size_t)(32 + kh) * 512);
        acc = __builtin_amdgcn_mfma_f32_32x32x16_bf16(ah, wh, acc, 0, 0, 0);
        acc = __builtin_amdgcn_mfma_f32_32x32x16_bf16(ah, wl, acc, 0, 0, 0);
        acc = __builtin_amdgcn_mfma_f32_32x32x16_bf16(al, wh, acc, 0, 0, 0);
    }

    // ---- epilogue: C/D layout col=lane&31, row=(r&3)+8*(r>>2)+4*(lane>>5) ----
    const int col = ntile * 32 + ln31;
    #pragma unroll
    for (int r = 0; r < 16; ++r) {
        const int mrow = (r & 3) + 8 * (r >> 2) + 4 * ln5;
        const int bb = mt * 32 + mrow;
        gates[((size_t)i * kB + bb) * kG5 + col] = acc[r];
    }
}

// ---------------------------------------------------------------------------
// Cell unit body (verified): unit = cellIdx*16 + bslice. Cell update + LN +
// h_new; writes h as A-frags + packed hi|lo u32 into `out`.
// ---------------------------------------------------------------------------
__device__ __forceinline__
void cell_unit_body(int d, int unit,
                    const float* __restrict__ bg,
                    const float* __restrict__ lns,
                    const float* __restrict__ lnb,
                    const float* __restrict__ gates,
                    float* __restrict__ c_bufs,
                    unsigned short* __restrict__ hfh,
                    unsigned short* __restrict__ hfl,
                    float* out) {
    __shared__ float red[8];
    const int tid = threadIdx.x;
    const int ilo = max(0, d - (kN - 1));
    const int i = ilo + (unit >> 4);
    const int j = d - i;
    const int b0 = (unit & 15) * 4;
    const int plane = kM * kB * kH;
    const float* c_prev = c_bufs + ((d + 1) & 1) * plane;
    float*       c_cur  = c_bufs + (d & 1) * plane;
    const int hp = d & 1;
    unsigned* outp = (unsigned*)out;

    const int u = tid;
    const float bg0 = bg[u];
    const float bg1 = bg[kH + u];
    const float bg2 = bg[2 * kH + u];
    const float bg3 = bg[3 * kH + u];
    const float bg4 = bg[4 * kH + u];
    const float lnsc = lns[u];
    const float lnbi = lnb[u];
    const int lane = tid & 63, wid = tid >> 6;
    const int kh = u >> 4, r = u & 15, jj = r & 7;

    for (int bl = 0; bl < 4; ++bl) {
        const int b = b0 + bl;
        const float* grow = gates + ((size_t)i * kB + b) * kG5;
        const float fc = grow[u] + bg0;
        const float fr = grow[kH + u] + bg1;
        const float ig = grow[2 * kH + u] + bg2;
        const float og = grow[3 * kH + u] + bg3;
        const float gg = grow[4 * kH + u] + bg4;
        const float cl = (j > 0) ? c_prev[((size_t)i * kB + b) * kH + u] : 0.f;
        const float cu = (i > 0) ? c_prev[((size_t)(i - 1) * kB + b) * kH + u] : 0.f;

        const float cell_v = sigm(fc) * cl + sigm(fr) * cu + sigm(ig) * tanhf(gg);
        c_cur[((size_t)i * kB + b) * kH + u] = cell_v;

        float s = cell_v, s2 = cell_v * cell_v;
        #pragma unroll
        for (int off = 32; off; off >>= 1) {
            s  += __shfl_down(s,  off, 64);
            s2 += __shfl_down(s2, off, 64);
        }
        if (lane == 0) { red[wid] = s; red[4 + wid] = s2; }
        __syncthreads();
        const float sum = red[0] + red[1] + red[2] + red[3];
        const float sq  = red[4] + red[5] + red[6] + red[7];
        __syncthreads();

        const float mu   = sum * (1.f / kH);
        const float var  = sq * (1.f / kH) - mu * mu;
        const float rstd = rsqrtf(var + 1e-6f);
        const float hv   = sigm(og) * tanhf((cell_v - mu) * rstd * lnsc + lnbi);

        unsigned short hb, lb;
        split1(hv, hb, lb);
        const int mt2 = b >> 5;
        const int fl = (b & 31) + 32 * (r >> 3);
        const size_t fo = ((size_t)(hp * kM + i)) * 16384
                        + (((size_t)(mt2 * 16 + kh) * 64 + fl) * 8 + jj);
        hfh[fo] = hb; hfl[fo] = lb;
        outp[(((size_t)b * kM + i) * kN + j) * kD + u] = (unsigned)hb | ((unsigned)lb << 16);
    }
}

// ---------------------------------------------------------------------------
// Persistent cooperative wavefront kernel: the whole 63-diagonal loop in one
// dispatch; grid.sync() replaces kernel launch + drain between phases.
// Work units are grid-strided so any co-resident grid size is correct.
// ---------------------------------------------------------------------------
__global__ __launch_bounds__(256, 2)
void wavefront(const unsigned short* __restrict__ xfh,
               const unsigned short* __restrict__ xfl,
               const unsigned short* __restrict__ whi,
               const unsigned short* __restrict__ wlo,
               unsigned short* __restrict__ hfh,
               unsigned short* __restrict__ hfl,
               const unsigned short* __restrict__ h0fh,
               const unsigned short* __restrict__ h0fl,
               float* __restrict__ gates,
               const float* __restrict__ bg,
               const float* __restrict__ lns,
               const float* __restrict__ lnb,
               float* __restrict__ c_bufs,
               float* out) {
    cg::grid_group grid = cg::this_grid();
    for (int d = 0; d < kM + kN - 1; ++d) {
        const int ilo = max(0, d - (kN - 1));
        const int ihi = min(d, kM - 1);
        const int ncell = ihi - ilo + 1;
        for (int u = blockIdx.x; u < ncell * 20; u += gridDim.x)
            gate_unit_body(d, u, xfh, xfl, whi, wlo, hfh, hfl, h0fh, h0fl, gates);
        __threadfence();
        grid.sync();
        for (int u = blockIdx.x; u < ncell * 16; u += gridDim.x)
            cell_unit_body(d, u, bg, lns, lnb, gates, c_bufs, hfh, hfl, out);
        __threadfence();
        grid.sync();
    }
}

// ---------------------------------------------------------------------------
// Fallback standalone kernels (round-3 verified): used if cooperative launch
// is unavailable or ws too small.
// ---------------------------------------------------------------------------
__global__ __launch_bounds__(256)
void gate_mfma_fast(int d,
                    const unsigned short* __restrict__ xfh,
                    const unsigned short* __restrict__ xfl,
                    const unsigned short* __restrict__ whi,
                    const unsigned short* __restrict__ wlo,
                    const unsigned short* __restrict__ hfh,
                    const unsigned short* __restrict__ hfl,
                    const unsigned short* __restrict__ h0fh,
                    const unsigned short* __restrict__ h0fl,
                    float* __restrict__ gates) {
    gate_unit_body(d, blockIdx.x, xfh, xfl, whi, wlo, hfh, hfl, h0fh, h0fl, gates);
}

__global__ __launch_bounds__(256)
void gate_mfma_legacy(int d,
               const float* __restrict__ x,
               const unsigned short* __restrict__ whi,
               const unsigned short* __restrict__ wlo,
               const unsigned short* __restrict__ hfh,
               const unsigned short* __restrict__ hfl,
               const unsigned short* __restrict__ h0fh,
               const unsigned short* __restrict__ h0fl,
               float* __restrict__ gates) {
    const int tid = threadIdx.x;
    const int ilo = max(0, d - (kN - 1));
    const int cell = blockIdx.x / 20;
    const int nc   = blockIdx.x % 20;
    const int i = ilo + cell;
    const int j = d - i;
    const int w = tid >> 6, lane = tid & 63;
    const int ln31 = lane & 31, ln5 = lane >> 5;
    const int mt = w & 1;
    const int ntile = nc * 2 + (w >> 1);
    const int hp = (d + 1) & 1;

    f32x16 acc;
    #pragma unroll
    for (int r = 0; r < 16; ++r) acc[r] = 0.f;

    const unsigned short* wph = whi + ((size_t)ntile * 3072 + lane) * 8;
    const unsigned short* wpl = wlo + ((size_t)ntile * 3072 + lane) * 8;

    const int b = mt * 32 + ln31;
    const float* xr = x + (((size_t)b * kM + i) * kN + j) * kD + ln5 * 8;
    #pragma unroll 4
    for (int kh = 0; kh < 16; ++kh) {
        const float4 v0 = *(const float4*)(xr + kh * 16);
        const float4 v1 = *(const float4*)(xr + kh * 16 + 4);
        unsigned short h8[8], l8[8];
        split1(v0.x, h8[0], l8[0]); split1(v0.y, h8[1], l8[1]);
        split1(v0.z, h8[2], l8[2]); split1(v0.w, h8[3], l8[3]);
        split1(v1.x, h8[4], l8[4]); split1(v1.y, h8[5], l8[5]);
        split1(v1.z, h8[6], l8[6]); split1(v1.w, h8[7], l8[7]);
        const bf16x8 ah = *(const bf16x8*)h8;
        const bf16x8 al = *(const bf16x8*)l8;
        const bf16x8 wh = *(const bf16x8*)(wph + (size_t)kh * 512);
        const bf16x8 wl = *(const bf16x8*)(wpl + (size_t)kh * 512);
        acc = __builtin_amdgcn_mfma_f32_32x32x16_bf16(ah, wh, acc, 0, 0, 0);
        acc = __builtin_amdgcn_mfma_f32_32x32x16_bf16(ah, wl, acc, 0, 0, 0);
        acc = __builtin_amdgcn_mfma_f32_32x32x16_bf16(al, wh, acc, 0, 0, 0);
    }

    const unsigned short *plh, *pll, *puh, *pul;
    if (j > 0) {
        const size_t o = ((size_t)(hp * kM + i)) * 16384 + ((size_t)(mt * 16) * 64 + lane) * 8;
        plh = hfh + o; pll = hfl + o;
    } else {
        plh = h0fh + lane * 8; pll = h0fl + lane * 8;
    }
    if (i > 0) {
        const size_t o = ((size_t)(hp * kM + (i - 1))) * 16384 + ((size_t)(mt * 16) * 64 + lane) * 8;
        puh = hfh + o; pul = hfl + o;
    } else {
        puh = h0fh + lane * 8; pul = h0fl + lane * 8;
    }

    #pragma unroll 4
    for (int kh = 0; kh < 16; ++kh) {
        const bf16x8 ah = *(const bf16x8*)(plh + (size_t)kh * 512);
        const bf16x8 al = *(const bf16x8*)(pll + (size_t)kh * 512);
        const bf16x8 wh = *(const bf16x8*)(wph + (size_t)(16 + kh) * 512);
        const bf16x8 wl = *(const bf16x8*)(wpl + (size_t)(16 + kh) * 512);
        acc = __builtin_amdgcn_mfma_f32_32x32x16_bf16(ah, wh, acc, 0, 0, 0);
        acc = __builtin_amdgcn_mfma_f32_32x32x16_bf16(ah, wl, acc, 0, 0, 0);
        acc = __builtin_amdgcn_mfma_f32_32x32x16_bf16(al, wh, acc, 0, 0, 0);
    }
    #pragma unroll 4
    for (int kh = 0; kh < 16; ++kh) {
        const bf16x8 ah = *(const bf16x8*)(puh + (size_t)kh * 512);
        const bf16x8 al = *(const bf16x8*)(pul + (size_t)kh * 512);
        const bf16x8 wh = *(const bf16x8*)(wph + (size_t)(32 + kh) * 512);
        const bf16x8 wl = *(const bf16x8*)(wpl + (size_t)(32 + kh) * 512);
        acc = __builtin_amdgcn_mfma_f32_32x32x16_bf16(ah, wh, acc, 0, 0, 0);
        acc = __builtin_amdgcn_mfma_f32_32x32x16_bf16(ah, wl, acc, 0, 0, 0);
        acc = __builtin_amdgcn_mfma_f32_32x32x16_bf16(al, wh, acc, 0, 0, 0);
    }

    const int col = ntile * 32 + ln31;
    #pragma unroll
    for (int r = 0; r < 16; ++r) {
        const int mrow = (r & 3) + 8 * (r >> 2) + 4 * ln5;
        const int bb = mt * 32 + mrow;
        gates[((size_t)i * kB + bb) * kG5 + col] = acc[r];
    }
}

__global__ __launch_bounds__(256)
void cell_ln(int d,
             const float* __restrict__ bg,
             const float* __restrict__ lns,
             const float* __restrict__ lnb,
             const float* __restrict__ gates,
             float* __restrict__ c_bufs,
             unsigned short* __restrict__ hfh,
             unsigned short* __restrict__ hfl,
             float* out) {
    cell_unit_body(d, blockIdx.x, bg, lns, lnb, gates, c_bufs, hfh, hfl, out);
}

// ---------------------------------------------------------------------------
// Final batched head GEMM: logits[R][:] = h[R][:] @ W_head + b_head, in-place
// over `out` (packed bf16 h -> fp32 logits). Block owns 64 rows x 256 cols.
// ---------------------------------------------------------------------------
__global__ __launch_bounds__(256)
void head_mfma(const unsigned short* __restrict__ whh,
               const unsigned short* __restrict__ whl,
               const float* __restrict__ bh,
               float* out) {
    const int tid = threadIdx.x;
    const int lane = tid & 63, w = tid >> 6;
    const int ln31 = lane & 31, ln5 = lane >> 5;
    const int r0 = blockIdx.x * 64;
    const int mt = w & 1, ng = w >> 1;
    unsigned* outp = (unsigned*)out;

    f32x16 acc[4];
    #pragma unroll
    for (int t = 0; t < 4; ++t)
        #pragma unroll
        for (int r = 0; r < 16; ++r) acc[t][r] = 0.f;

    const int m = r0 + mt * 32 + ln31;
    const unsigned* arow = outp + (size_t)m * kD + ln5 * 8;

    #pragma unroll 2
    for (int kc = 0; kc < 16; ++kc) {
        const uint4 p0 = *(const uint4*)(arow + kc * 16);
        const uint4 p1 = *(const uint4*)(arow + kc * 16 + 4);
        unsigned short h8[8], l8[8];
        h8[0] = (unsigned short)(p0.x & 0xffffu); l8[0] = (unsigned short)(p0.x >> 16);
        h8[1] = (unsigned short)(p0.y & 0xffffu); l8[1] = (unsigned short)(p0.y >> 16);
        h8[2] = (unsigned short)(p0.z & 0xffffu); l8[2] = (unsigned short)(p0.z >> 16);
        h8[3] = (unsigned short)(p0.w & 0xffffu); l8[3] = (unsigned short)(p0.w >> 16);
        h8[4] = (unsigned short)(p1.x & 0xffffu); l8[4] = (unsigned short)(p1.x >> 16);
        h8[5] = (unsigned short)(p1.y & 0xffffu); l8[5] = (unsigned short)(p1.y >> 16);
        h8[6] = (unsigned short)(p1.z & 0xffffu); l8[6] = (unsigned short)(p1.z >> 16);
        h8[7] = (unsigned short)(p1.w & 0xffffu); l8[7] = (unsigned short)(p1.w >> 16);
        const bf16x8 ah = *(const bf16x8*)h8;
        const bf16x8 al = *(const bf16x8*)l8;
        #pragma unroll
        for (int t = 0; t < 4; ++t) {
            const int nt = ng * 4 + t;
            const size_t g = ((size_t)(nt * 16 + kc) * 64 + lane) * 8;
            const bf16x8 wh = *(const bf16x8*)(whh + g);
            const bf16x8 wl = *(const bf16x8*)(whl + g);
            acc[t] = __builtin_amdgcn_mfma_f32_32x32x16_bf16(ah, wh, acc[t], 0, 0, 0);
            acc[t] = __builtin_amdgcn_mfma_f32_32x32x16_bf16(ah, wl, acc[t], 0, 0, 0);
            acc[t] = __builtin_amdgcn_mfma_f32_32x32x16_bf16(al, wh, acc[t], 0, 0, 0);
        }
    }

    __syncthreads();   // all packed-h reads done before any in-place store

    #pragma unroll
    for (int t = 0; t < 4; ++t) {
        const int col = (ng * 4 + t) * 32 + ln31;
        const float bb = bh[col];
        #pragma unroll
        for (int r = 0; r < 16; ++r) {
            const int row = r0 + mt * 32 + (r & 3) + 8 * (r >> 2) + 4 * ln5;
            out[(size_t)row * kD + col] = acc[t][r] + bb;
        }
    }
}

extern "C" void kernel_launch(void* const* d_in, const int* in_sizes, int n_in,
                              void* d_out, int out_size, void* d_ws, size_t ws_size,
                              hipStream_t stream) {
    const float* x     = (const float*)d_in[0];
    const float* Wg    = (const float*)d_in[1];
    const float* bg    = (const float*)d_in[2];
    const float* lns   = (const float*)d_in[3];
    const float* lnb   = (const float*)d_in[4];
    const float* Wh    = (const float*)d_in[5];
    const float* bh    = (const float*)d_in[6];
    const float* hinit = (const float*)d_in[7];
    float* out = (float*)d_out;

    // ws layout (byte offsets, all 16B-aligned)
    char* wsb = (char*)d_ws;
    float*          gates  = (float*)(wsb);                              // 10,485,760 B
    float*          c_bufs = (float*)(wsb + 10485760);                   //  4,194,304 B
    unsigned short* hfh    = (unsigned short*)(wsb + 14680064);          //  2,097,152 B
    unsigned short* hfl    = (unsigned short*)(wsb + 16777216);          //  2,097,152 B
    unsigned short* whi    = (unsigned short*)(wsb + 18874368);          //  1,966,080 B
    unsigned short* wlo    = (unsigned short*)(wsb + 20840448);          //  1,966,080 B
    unsigned short* h0fh   = (unsigned short*)(wsb + 22806528);          //     16,384 B
    unsigned short* h0fl   = (unsigned short*)(wsb + 22822912);          //     16,384 B
    unsigned short* whh    = (unsigned short*)(wsb + 22839296);          //    131,072 B
    unsigned short* whl    = (unsigned short*)(wsb + 22970368);          //    131,072 B
    unsigned short* xfh    = (unsigned short*)(wsb + 23101440);          // 33,554,432 B
    unsigned short* xfl    = (unsigned short*)(wsb + 56655872);          // 33,554,432 B
    const size_t kWsNeededFast = 90210304;                               // end of xfl

    const bool fast = (ws_size >= kWsNeededFast);

    hipLaunchKernelGGL(prep_w,  dim3(480), dim3(256), 0, stream, Wg, whi, wlo);
    hipLaunchKernelGGL(prep_wh, dim3(32),  dim3(256), 0, stream, Wh, whh, whl);
    hipLaunchKernelGGL(prep_h0f, dim3(4),  dim3(256), 0, stream, hinit, h0fh, h0fl);

    bool coop_done = false;
    if (fast) {
        hipLaunchKernelGGL(prep_x, dim3(8192), dim3(256), 0, stream, x, xfh, xfl);

        // One-time cooperative capacity query (host-side, graph-capture safe).
        static int coopGrid = -1;
        if (coopGrid < 0) {
            int perCU = 0;
            if (hipOccupancyMaxActiveBlocksPerMultiprocessor(&perCU, wavefront, 256, 0)
                    != hipSuccess || perCU < 1) {
                coopGrid = 0;
            } else {
                int nCU = 256;
                hipDeviceProp_t prop;
                int dev = 0;
                if (hipGetDevice(&dev) == hipSuccess &&
                    hipGetDeviceProperties(&prop, dev) == hipSuccess &&
                    prop.multiProcessorCount > 0)
                    nCU = prop.multiProcessorCount;
                long cap = (long)perCU * (long)nCU;
                coopGrid = (int)(cap < 640 ? cap : 640);
            }
        }

        if (coopGrid > 0) {
            void* args[] = {
                (void*)&xfh, (void*)&xfl, (void*)&whi, (void*)&wlo,
                (void*)&hfh, (void*)&hfl, (void*)&h0fh, (void*)&h0fl,
                (void*)&gates, (void*)&bg, (void*)&lns, (void*)&lnb,
                (void*)&c_bufs, (void*)&out
            };
            hipError_t e = hipLaunchCooperativeKernel(wavefront, dim3(coopGrid), dim3(256),
                                                      args, 0, stream);
            coop_done = (e == hipSuccess);
        }
    }

    if (!coop_done) {
        for (int d = 0; d < kM + kN - 1; ++d) {
            const int ilo = max(0, d - (kN - 1));
            const int ihi = min(d, kM - 1);
            const int ncell = ihi - ilo + 1;
            if (fast) {
                hipLaunchKernelGGL(gate_mfma_fast, dim3(ncell * 20), dim3(256), 0, stream,
                                   d, xfh, xfl, whi, wlo, hfh, hfl, h0fh, h0fl, gates);
            } else {
                hipLaunchKernelGGL(gate_mfma_legacy, dim3(ncell * 20), dim3(256), 0, stream,
                                   d, x, whi, wlo, hfh, hfl, h0fh, h0fl, gates);
            }
            hipLaunchKernelGGL(cell_ln, dim3(ncell * 16), dim3(256), 0, stream,
                               d, bg, lns, lnb, gates, c_bufs, hfh, hfl, out);
        }
    }
    hipLaunchKernelGGL(head_mfma, dim3(1024), dim3(256), 0, stream, whh, whl, bh, out);
}

// Round 5
// 5478.790 us; speedup vs baseline: 2.8167x; 2.8167x over previous
//
#include <hip/hip_runtime.h>

// Problem dims (hardcoded per reference)
constexpr int kB   = 64;    // batch
constexpr int kM   = 32;    // rows
constexpr int kN   = 32;    // cols
constexpr int kD   = 256;   // input/vocab dim
constexpr int kH   = 256;   // hidden
constexpr int kG5  = 1280;  // 5H

typedef __attribute__((ext_vector_type(8)))  short bf16x8;
typedef __attribute__((ext_vector_type(16))) float f32x16;

__device__ __forceinline__ float bu2f(unsigned short u) {
    return __uint_as_float(((unsigned)u) << 16);
}
__device__ __forceinline__ unsigned short f2bu(float f) {
    unsigned u = __float_as_uint(f);
    return (unsigned short)((u + 0x7FFF + ((u >> 16) & 1)) >> 16);   // RNE
}
__device__ __forceinline__ void split1(float a, unsigned short& hi, unsigned short& lo) {
    hi = f2bu(a);
    lo = f2bu(a - bu2f(hi));     // |residual after lo| <= 2^-18 |a|
}
__device__ __forceinline__ float sigm(float x) { return 1.f / (1.f + expf(-x)); }

// ---------------------------------------------------------------------------
// Prep 1: swizzle Wg (fp32 [768][1280]) into MFMA-B-fragment-contiguous bf16
// hi/lo panels. B-frag for v_mfma_f32_32x32x16_bf16: lane l holds
// B[k=(l>>5)*8+j][n=l&31]. 40 ntiles x 48 chunks.
// ---------------------------------------------------------------------------
__global__ void prep_w(const float* __restrict__ Wg,
                       unsigned short* __restrict__ whi,
                       unsigned short* __restrict__ wlo) {
    const int t = blockIdx.x * 256 + threadIdx.x;     // 0..122879
    const int lane = t & 63;
    const int rest = t >> 6;
    const int s = rest % 48;
    const int ntile = rest / 48;
    const int n = ntile * 32 + (lane & 31);
    const int kb = s * 16 + (lane >> 5) * 8;
    unsigned short h8[8], l8[8];
    #pragma unroll
    for (int j = 0; j < 8; ++j) {
        const float a = Wg[(size_t)(kb + j) * kG5 + n];
        split1(a, h8[j], l8[j]);
    }
    *(bf16x8*)(whi + (size_t)t * 8) = *(const bf16x8*)h8;
    *(bf16x8*)(wlo + (size_t)t * 8) = *(const bf16x8*)l8;
}

// Prep 2: W_head (fp32 [256][256]) -> B-frag bf16 hi/lo (8 ntiles x 16 chunks)
__global__ void prep_wh(const float* __restrict__ Wh,
                        unsigned short* __restrict__ whh,
                        unsigned short* __restrict__ whl) {
    const int t = blockIdx.x * 256 + threadIdx.x;     // 0..8191
    const int lane = t & 63;
    const int rest = t >> 6;                          // 0..127
    const int kc = rest & 15;
    const int nt = rest >> 4;                         // 0..7
    const int n = nt * 32 + (lane & 31);
    const int kb = kc * 16 + (lane >> 5) * 8;
    unsigned short h8[8], l8[8];
    #pragma unroll
    for (int j = 0; j < 8; ++j) {
        const float a = Wh[(size_t)(kb + j) * kD + n];
        split1(a, h8[j], l8[j]);
    }
    *(bf16x8*)(whh + (size_t)t * 8) = *(const bf16x8*)h8;
    *(bf16x8*)(whl + (size_t)t * 8) = *(const bf16x8*)l8;
}

// Prep 3: h_init -> A-frag layout [kh 0..15][lane][8]; also zeros the per-cell
// barrier counters (63 diagonals x 32 cells).
__global__ void prep_h0f(const float* __restrict__ hinit,
                         unsigned short* __restrict__ h0fh,
                         unsigned short* __restrict__ h0fl,
                         unsigned* __restrict__ cnt) {
    const int idx = blockIdx.x * 256 + threadIdx.x;   // 0..2047
    if (idx < 1024) {
        const int lane = idx & 63;
        const int kh = idx >> 6;
        const int k0 = kh * 16 + (lane >> 5) * 8;
        unsigned short h8[8], l8[8];
        #pragma unroll
        for (int j = 0; j < 8; ++j) split1(hinit[k0 + j], h8[j], l8[j]);
        *(bf16x8*)(h0fh + (size_t)idx * 8) = *(const bf16x8*)h8;
        *(bf16x8*)(h0fl + (size_t)idx * 8) = *(const bf16x8*)l8;
    }
    if (idx < 63 * 32) cnt[idx] = 0;
}

// ---------------------------------------------------------------------------
// Prep 4: pre-split ALL of x into A-frag bf16 hi/lo panels.
// Per (cell,mt): [kh 0..15][lane 0..63][8].
// ---------------------------------------------------------------------------
__global__ void prep_x(const float* __restrict__ x,
                       unsigned short* __restrict__ xfh,
                       unsigned short* __restrict__ xfl) {
    const int t = blockIdx.x * 256 + threadIdx.x;     // 0..2097151
    const int kq   = t & 31;            // k/8
    const int b    = (t >> 5) & 63;
    const int cell = t >> 11;           // i*kN+j, 0..1023
    const float* src = x + (((size_t)b * 1024 + cell) * kD + kq * 8);
    unsigned short h8[8], l8[8];
    #pragma unroll
    for (int j = 0; j < 8; ++j) split1(src[j], h8[j], l8[j]);
    const int mt = b >> 5, kh = kq >> 1;
    const int l  = (b & 31) + 32 * (kq & 1);
    const size_t dst = ((((size_t)cell * 2 + mt) * 16 + kh) * 64 + l) * 8;
    *(bf16x8*)(xfh + dst) = *(const bf16x8*)h8;
    *(bf16x8*)(xfl + dst) = *(const bf16x8*)l8;
}

// ---------------------------------------------------------------------------
// Gate unit body (verified round 3): unit = cell*20 + nc. Wave = 1 m-tile
// x 1 n-tile, 144 MFMA, barrier-free, all A operands pre-swizzled.
// ---------------------------------------------------------------------------
__device__ __forceinline__
void gate_unit_body(int d, int unit,
                    const unsigned short* __restrict__ xfh,
                    const unsigned short* __restrict__ xfl,
                    const unsigned short* __restrict__ whi,
                    const unsigned short* __restrict__ wlo,
                    const unsigned short* __restrict__ hfh,
                    const unsigned short* __restrict__ hfl,
                    const unsigned short* __restrict__ h0fh,
                    const unsigned short* __restrict__ h0fl,
                    float* __restrict__ gates) {
    const int tid = threadIdx.x;
    const int ilo = max(0, d - (kN - 1));
    const int cell = unit / 20;
    const int nc   = unit % 20;
    const int i = ilo + cell;
    const int j = d - i;
    const int w = tid >> 6, lane = tid & 63;
    const int ln31 = lane & 31, ln5 = lane >> 5;
    const int mt = w & 1;                        // m-tile (batch rows mt*32..)
    const int ntile = nc * 2 + (w >> 1);         // global 32-col tile
    const int hp = (d + 1) & 1;                  // h plane written at diag d-1
    const int cl = i * kN + j;                   // linear cell index

    f32x16 acc;
    #pragma unroll
    for (int r = 0; r < 16; ++r) acc[r] = 0.f;

    const unsigned short* wph = whi + ((size_t)ntile * 3072 + lane) * 8;
    const unsigned short* wpl = wlo + ((size_t)ntile * 3072 + lane) * 8;

    // ---- x part: chunks 0..15, pre-split frags ----
    const unsigned short* xph = xfh + (((size_t)cl * 2 + mt) * 16 * 64 + lane) * 8;
    const unsigned short* xpl = xfl + (((size_t)cl * 2 + mt) * 16 * 64 + lane) * 8;
    #pragma unroll 4
    for (int kh = 0; kh < 16; ++kh) {
        const bf16x8 ah = *(const bf16x8*)(xph + (size_t)kh * 512);
        const bf16x8 al = *(const bf16x8*)(xpl + (size_t)kh * 512);
        const bf16x8 wh = *(const bf16x8*)(wph + (size_t)kh * 512);
        const bf16x8 wl = *(const bf16x8*)(wpl + (size_t)kh * 512);
        acc = __builtin_amdgcn_mfma_f32_32x32x16_bf16(ah, wh, acc, 0, 0, 0);
        acc = __builtin_amdgcn_mfma_f32_32x32x16_bf16(ah, wl, acc, 0, 0, 0);
        acc = __builtin_amdgcn_mfma_f32_32x32x16_bf16(al, wh, acc, 0, 0, 0);
    }

    // ---- h_l part: chunks 16..31; h_u part: chunks 32..47 ----
    const unsigned short *plh, *pll, *puh, *pul;
    if (j > 0) {
        const size_t o = ((size_t)(hp * kM + i)) * 16384 + ((size_t)(mt * 16) * 64 + lane) * 8;
        plh = hfh + o; pll = hfl + o;
    } else {
        plh = h0fh + lane * 8; pll = h0fl + lane * 8;
    }
    if (i > 0) {
        const size_t o = ((size_t)(hp * kM + (i - 1))) * 16384 + ((size_t)(mt * 16) * 64 + lane) * 8;
        puh = hfh + o; pul = hfl + o;
    } else {
        puh = h0fh + lane * 8; pul = h0fl + lane * 8;
    }

    #pragma unroll 4
    for (int kh = 0; kh < 16; ++kh) {
        const bf16x8 ah = *(const bf16x8*)(plh + (size_t)kh * 512);
        const bf16x8 al = *(const bf16x8*)(pll + (size_t)kh * 512);
        const bf16x8 wh = *(const bf16x8*)(wph + (size_t)(16 + kh) * 512);
        const bf16x8 wl = *(const bf16x8*)(wpl + (size_t)(16 + kh) * 512);
        acc = __builtin_amdgcn_mfma_f32_32x32x16_bf16(ah, wh, acc, 0, 0, 0);
        acc = __builtin_amdgcn_mfma_f32_32x32x16_bf16(ah, wl, acc, 0, 0, 0);
        acc = __builtin_amdgcn_mfma_f32_32x32x16_bf16(al, wh, acc, 0, 0, 0);
    }
    #pragma unroll 4
    for (int kh = 0; kh < 16; ++kh) {
        const bf16x8 ah = *(const bf16x8*)(puh + (size_t)kh * 512);
        const bf16x8 al = *(const bf16x8*)(pul + (size_t)kh * 512);
        const bf16x8 wh = *(const bf16x8*)(wph + (size_t)(32 + kh) * 512);
        const bf16x8 wl = *(const bf16x8*)(wpl + (size_t)(32 + kh) * 512);
        acc = __builtin_amdgcn_mfma_f32_32x32x16_bf16(ah, wh, acc, 0, 0, 0);
        acc = __builtin_amdgcn_mfma_f32_32x32x16_bf16(ah, wl, acc, 0, 0, 0);
        acc = __builtin_amdgcn_mfma_f32_32x32x16_bf16(al, wh, acc, 0, 0, 0);
    }

    // ---- epilogue: C/D layout col=lane&31, row=(r&3)+8*(r>>2)+4*(lane>>5) ----
    const int col = ntile * 32 + ln31;
    #pragma unroll
    for (int r = 0; r < 16; ++r) {
        const int mrow = (r & 3) + 8 * (r >> 2) + 4 * ln5;
        const int bb = mt * 32 + mrow;
        gates[((size_t)i * kB + bb) * kG5 + col] = acc[r];
    }
}

// ---------------------------------------------------------------------------
// Cell unit body (verified): unit = cellIdx*16 + bslice. Cell update + LN +
// h_new; writes h as A-frags + packed hi|lo u32 into `out`.
// ---------------------------------------------------------------------------
__device__ __forceinline__
void cell_unit_body(int d, int unit,
                    const float* __restrict__ bg,
                    const float* __restrict__ lns,
                    const float* __restrict__ lnb,
                    const float* __restrict__ gates,
                    float* __restrict__ c_bufs,
                    unsigned short* __restrict__ hfh,
                    unsigned short* __restrict__ hfl,
                    float* out) {
    __shared__ float red[8];
    const int tid = threadIdx.x;
    const int ilo = max(0, d - (kN - 1));
    const int i = ilo + (unit >> 4);
    const int j = d - i;
    const int b0 = (unit & 15) * 4;
    const int plane = kM * kB * kH;
    const float* c_prev = c_bufs + ((d + 1) & 1) * plane;
    float*       c_cur  = c_bufs + (d & 1) * plane;
    const int hp = d & 1;
    unsigned* outp = (unsigned*)out;

    const int u = tid;
    const float bg0 = bg[u];
    const float bg1 = bg[kH + u];
    const float bg2 = bg[2 * kH + u];
    const float bg3 = bg[3 * kH + u];
    const float bg4 = bg[4 * kH + u];
    const float lnsc = lns[u];
    const float lnbi = lnb[u];
    const int lane = tid & 63, wid = tid >> 6;
    const int kh = u >> 4, r = u & 15, jj = r & 7;

    for (int bl = 0; bl < 4; ++bl) {
        const int b = b0 + bl;
        const float* grow = gates + ((size_t)i * kB + b) * kG5;
        const float fc = grow[u] + bg0;
        const float fr = grow[kH + u] + bg1;
        const float ig = grow[2 * kH + u] + bg2;
        const float og = grow[3 * kH + u] + bg3;
        const float gg = grow[4 * kH + u] + bg4;
        const float cl = (j > 0) ? c_prev[((size_t)i * kB + b) * kH + u] : 0.f;
        const float cu = (i > 0) ? c_prev[((size_t)(i - 1) * kB + b) * kH + u] : 0.f;

        const float cell_v = sigm(fc) * cl + sigm(fr) * cu + sigm(ig) * tanhf(gg);
        c_cur[((size_t)i * kB + b) * kH + u] = cell_v;

        float s = cell_v, s2 = cell_v * cell_v;
        #pragma unroll
        for (int off = 32; off; off >>= 1) {
            s  += __shfl_down(s,  off, 64);
            s2 += __shfl_down(s2, off, 64);
        }
        if (lane == 0) { red[wid] = s; red[4 + wid] = s2; }
        __syncthreads();
        const float sum = red[0] + red[1] + red[2] + red[3];
        const float sq  = red[4] + red[5] + red[6] + red[7];
        __syncthreads();

        const float mu   = sum * (1.f / kH);
        const float var  = sq * (1.f / kH) - mu * mu;
        const float rstd = rsqrtf(var + 1e-6f);
        const float hv   = sigm(og) * tanhf((cell_v - mu) * rstd * lnsc + lnbi);

        unsigned short hb, lb;
        split1(hv, hb, lb);
        const int mt2 = b >> 5;
        const int fl = (b & 31) + 32 * (r >> 3);
        const size_t fo = ((size_t)(hp * kM + i)) * 16384
                        + (((size_t)(mt2 * 16 + kh) * 64 + fl) * 8 + jj);
        hfh[fo] = hb; hfl[fo] = lb;
        outp[(((size_t)b * kM + i) * kN + j) * kD + u] = (unsigned)hb | ((unsigned)lb << 16);
    }
}

// ---------------------------------------------------------------------------
// Fused gate+cell per diagonal. Block = (cell, nc of 20). Each block computes
// its gate unit, signals a per-(d,cell) counter, spins until all 20 of the
// cell's blocks arrive (device-scope; only 20 participants, not grid-wide —
// round-4 lesson: grid.sync() costs ~145 us here), then blocks nc<16 run the
// cell unit. Co-residency guaranteed: grid <= 640, __launch_bounds__(256,4)
// => >= 4 blocks/CU => capacity 1024. Counters indexed by (d,cell): written
// once per launch, zeroed in prep_h0f.
// ---------------------------------------------------------------------------
__global__ __launch_bounds__(256, 4)
void gate_cell(int d,
               const unsigned short* __restrict__ xfh,
               const unsigned short* __restrict__ xfl,
               const unsigned short* __restrict__ whi,
               const unsigned short* __restrict__ wlo,
               unsigned short* __restrict__ hfh,
               unsigned short* __restrict__ hfl,
               const unsigned short* __restrict__ h0fh,
               const unsigned short* __restrict__ h0fl,
               float* __restrict__ gates,
               const float* __restrict__ bg,
               const float* __restrict__ lns,
               const float* __restrict__ lnb,
               float* __restrict__ c_bufs,
               float* out,
               unsigned* __restrict__ cnt) {
    const int cell = blockIdx.x / 20;
    const int nc   = blockIdx.x % 20;

    gate_unit_body(d, blockIdx.x, xfh, xfl, whi, wlo, hfh, hfl, h0fh, h0fl, gates);

    // release: all block stores visible before signal
    __threadfence();
    __syncthreads();
    unsigned* c = cnt + d * 32 + cell;
    if (threadIdx.x == 0) {
        __hip_atomic_fetch_add(c, 1u, __ATOMIC_RELEASE, __HIP_MEMORY_SCOPE_AGENT);
        while (__hip_atomic_load(c, __ATOMIC_ACQUIRE, __HIP_MEMORY_SCOPE_AGENT) < 20u) {}
    }
    __syncthreads();

    if (nc < 16)
        cell_unit_body(d, cell * 16 + nc, bg, lns, lnb, gates, c_bufs, hfh, hfl, out);
}

// ---------------------------------------------------------------------------
// Fallback standalone kernels (round-3 verified): used if ws too small.
// ---------------------------------------------------------------------------
__global__ __launch_bounds__(256)
void gate_mfma_legacy(int d,
               const float* __restrict__ x,
               const unsigned short* __restrict__ whi,
               const unsigned short* __restrict__ wlo,
               const unsigned short* __restrict__ hfh,
               const unsigned short* __restrict__ hfl,
               const unsigned short* __restrict__ h0fh,
               const unsigned short* __restrict__ h0fl,
               float* __restrict__ gates) {
    const int tid = threadIdx.x;
    const int ilo = max(0, d - (kN - 1));
    const int cell = blockIdx.x / 20;
    const int nc   = blockIdx.x % 20;
    const int i = ilo + cell;
    const int j = d - i;
    const int w = tid >> 6, lane = tid & 63;
    const int ln31 = lane & 31, ln5 = lane >> 5;
    const int mt = w & 1;
    const int ntile = nc * 2 + (w >> 1);
    const int hp = (d + 1) & 1;

    f32x16 acc;
    #pragma unroll
    for (int r = 0; r < 16; ++r) acc[r] = 0.f;

    const unsigned short* wph = whi + ((size_t)ntile * 3072 + lane) * 8;
    const unsigned short* wpl = wlo + ((size_t)ntile * 3072 + lane) * 8;

    const int b = mt * 32 + ln31;
    const float* xr = x + (((size_t)b * kM + i) * kN + j) * kD + ln5 * 8;
    #pragma unroll 4
    for (int kh = 0; kh < 16; ++kh) {
        const float4 v0 = *(const float4*)(xr + kh * 16);
        const float4 v1 = *(const float4*)(xr + kh * 16 + 4);
        unsigned short h8[8], l8[8];
        split1(v0.x, h8[0], l8[0]); split1(v0.y, h8[1], l8[1]);
        split1(v0.z, h8[2], l8[2]); split1(v0.w, h8[3], l8[3]);
        split1(v1.x, h8[4], l8[4]); split1(v1.y, h8[5], l8[5]);
        split1(v1.z, h8[6], l8[6]); split1(v1.w, h8[7], l8[7]);
        const bf16x8 ah = *(const bf16x8*)h8;
        const bf16x8 al = *(const bf16x8*)l8;
        const bf16x8 wh = *(const bf16x8*)(wph + (size_t)kh * 512);
        const bf16x8 wl = *(const bf16x8*)(wpl + (size_t)kh * 512);
        acc = __builtin_amdgcn_mfma_f32_32x32x16_bf16(ah, wh, acc, 0, 0, 0);
        acc = __builtin_amdgcn_mfma_f32_32x32x16_bf16(ah, wl, acc, 0, 0, 0);
        acc = __builtin_amdgcn_mfma_f32_32x32x16_bf16(al, wh, acc, 0, 0, 0);
    }

    const unsigned short *plh, *pll, *puh, *pul;
    if (j > 0) {
        const size_t o = ((size_t)(hp * kM + i)) * 16384 + ((size_t)(mt * 16) * 64 + lane) * 8;
        plh = hfh + o; pll = hfl + o;
    } else {
        plh = h0fh + lane * 8; pll = h0fl + lane * 8;
    }
    if (i > 0) {
        const size_t o = ((size_t)(hp * kM + (i - 1))) * 16384 + ((size_t)(mt * 16) * 64 + lane) * 8;
        puh = hfh + o; pul = hfl + o;
    } else {
        puh = h0fh + lane * 8; pul = h0fl + lane * 8;
    }

    #pragma unroll 4
    for (int kh = 0; kh < 16; ++kh) {
        const bf16x8 ah = *(const bf16x8*)(plh + (size_t)kh * 512);
        const bf16x8 al = *(const bf16x8*)(pll + (size_t)kh * 512);
        const bf16x8 wh = *(const bf16x8*)(wph + (size_t)(16 + kh) * 512);
        const bf16x8 wl = *(const bf16x8*)(wpl + (size_t)(16 + kh) * 512);
        acc = __builtin_amdgcn_mfma_f32_32x32x16_bf16(ah, wh, acc, 0, 0, 0);
        acc = __builtin_amdgcn_mfma_f32_32x32x16_bf16(ah, wl, acc, 0, 0, 0);
        acc = __builtin_amdgcn_mfma_f32_32x32x16_bf16(al, wh, acc, 0, 0, 0);
    }
    #pragma unroll 4
    for (int kh = 0; kh < 16; ++kh) {
        const bf16x8 ah = *(const bf16x8*)(puh + (size_t)kh * 512);
        const bf16x8 al = *(const bf16x8*)(pul + (size_t)kh * 512);
        const bf16x8 wh = *(const bf16x8*)(wph + (size_t)(32 + kh) * 512);
        const bf16x8 wl = *(const bf16x8*)(wpl + (size_t)(32 + kh) * 512);
        acc = __builtin_amdgcn_mfma_f32_32x32x16_bf16(ah, wh, acc, 0, 0, 0);
        acc = __builtin_amdgcn_mfma_f32_32x32x16_bf16(ah, wl, acc, 0, 0, 0);
        acc = __builtin_amdgcn_mfma_f32_32x32x16_bf16(al, wh, acc, 0, 0, 0);
    }

    const int col = ntile * 32 + ln31;
    #pragma unroll
    for (int r = 0; r < 16; ++r) {
        const int mrow = (r & 3) + 8 * (r >> 2) + 4 * ln5;
        const int bb = mt * 32 + mrow;
        gates[((size_t)i * kB + bb) * kG5 + col] = acc[r];
    }
}

__global__ __launch_bounds__(256)
void cell_ln(int d,
             const float* __restrict__ bg,
             const float* __restrict__ lns,
             const float* __restrict__ lnb,
             const float* __restrict__ gates,
             float* __restrict__ c_bufs,
             unsigned short* __restrict__ hfh,
             unsigned short* __restrict__ hfl,
             float* out) {
    cell_unit_body(d, blockIdx.x, bg, lns, lnb, gates, c_bufs, hfh, hfl, out);
}

// ---------------------------------------------------------------------------
// Final batched head GEMM: logits[R][:] = h[R][:] @ W_head + b_head, in-place
// over `out` (packed bf16 h -> fp32 logits). Block owns 64 rows x 256 cols.
// ---------------------------------------------------------------------------
__global__ __launch_bounds__(256)
void head_mfma(const unsigned short* __restrict__ whh,
               const unsigned short* __restrict__ whl,
               const float* __restrict__ bh,
               float* out) {
    const int tid = threadIdx.x;
    const int lane = tid & 63, w = tid >> 6;
    const int ln31 = lane & 31, ln5 = lane >> 5;
    const int r0 = blockIdx.x * 64;
    const int mt = w & 1, ng = w >> 1;
    unsigned* outp = (unsigned*)out;

    f32x16 acc[4];
    #pragma unroll
    for (int t = 0; t < 4; ++t)
        #pragma unroll
        for (int r = 0; r < 16; ++r) acc[t][r] = 0.f;

    const int m = r0 + mt * 32 + ln31;
    const unsigned* arow = outp + (size_t)m * kD + ln5 * 8;

    #pragma unroll 2
    for (int kc = 0; kc < 16; ++kc) {
        const uint4 p0 = *(const uint4*)(arow + kc * 16);
        const uint4 p1 = *(const uint4*)(arow + kc * 16 + 4);
        unsigned short h8[8], l8[8];
        h8[0] = (unsigned short)(p0.x & 0xffffu); l8[0] = (unsigned short)(p0.x >> 16);
        h8[1] = (unsigned short)(p0.y & 0xffffu); l8[1] = (unsigned short)(p0.y >> 16);
        h8[2] = (unsigned short)(p0.z & 0xffffu); l8[2] = (unsigned short)(p0.z >> 16);
        h8[3] = (unsigned short)(p0.w & 0xffffu); l8[3] = (unsigned short)(p0.w >> 16);
        h8[4] = (unsigned short)(p1.x & 0xffffu); l8[4] = (unsigned short)(p1.x >> 16);
        h8[5] = (unsigned short)(p1.y & 0xffffu); l8[5] = (unsigned short)(p1.y >> 16);
        h8[6] = (unsigned short)(p1.z & 0xffffu); l8[6] = (unsigned short)(p1.z >> 16);
        h8[7] = (unsigned short)(p1.w & 0xffffu); l8[7] = (unsigned short)(p1.w >> 16);
        const bf16x8 ah = *(const bf16x8*)h8;
        const bf16x8 al = *(const bf16x8*)l8;
        #pragma unroll
        for (int t = 0; t < 4; ++t) {
            const int nt = ng * 4 + t;
            const size_t g = ((size_t)(nt * 16 + kc) * 64 + lane) * 8;
            const bf16x8 wh = *(const bf16x8*)(whh + g);
            const bf16x8 wl = *(const bf16x8*)(whl + g);
            acc[t] = __builtin_amdgcn_mfma_f32_32x32x16_bf16(ah, wh, acc[t], 0, 0, 0);
            acc[t] = __builtin_amdgcn_mfma_f32_32x32x16_bf16(ah, wl, acc[t], 0, 0, 0);
            acc[t] = __builtin_amdgcn_mfma_f32_32x32x16_bf16(al, wh, acc[t], 0, 0, 0);
        }
    }

    __syncthreads();   // all packed-h reads done before any in-place store

    #pragma unroll
    for (int t = 0; t < 4; ++t) {
        const int col = (ng * 4 + t) * 32 + ln31;
        const float bb = bh[col];
        #pragma unroll
        for (int r = 0; r < 16; ++r) {
            const int row = r0 + mt * 32 + (r & 3) + 8 * (r >> 2) + 4 * ln5;
            out[(size_t)row * kD + col] = acc[t][r] + bb;
        }
    }
}

extern "C" void kernel_launch(void* const* d_in, const int* in_sizes, int n_in,
                              void* d_out, int out_size, void* d_ws, size_t ws_size,
                              hipStream_t stream) {
    const float* x     = (const float*)d_in[0];
    const float* Wg    = (const float*)d_in[1];
    const float* bg    = (const float*)d_in[2];
    const float* lns   = (const float*)d_in[3];
    const float* lnb   = (const float*)d_in[4];
    const float* Wh    = (const float*)d_in[5];
    const float* bh    = (const float*)d_in[6];
    const float* hinit = (const float*)d_in[7];
    float* out = (float*)d_out;

    // ws layout (byte offsets, all 16B-aligned)
    char* wsb = (char*)d_ws;
    float*          gates  = (float*)(wsb);                              // 10,485,760 B
    float*          c_bufs = (float*)(wsb + 10485760);                   //  4,194,304 B
    unsigned short* hfh    = (unsigned short*)(wsb + 14680064);          //  2,097,152 B
    unsigned short* hfl    = (unsigned short*)(wsb + 16777216);          //  2,097,152 B
    unsigned short* whi    = (unsigned short*)(wsb + 18874368);          //  1,966,080 B
    unsigned short* wlo    = (unsigned short*)(wsb + 20840448);          //  1,966,080 B
    unsigned short* h0fh   = (unsigned short*)(wsb + 22806528);          //     16,384 B
    unsigned short* h0fl   = (unsigned short*)(wsb + 22822912);          //     16,384 B
    unsigned short* whh    = (unsigned short*)(wsb + 22839296);          //    131,072 B
    unsigned short* whl    = (unsigned short*)(wsb + 22970368);          //    131,072 B
    unsigned*       cnt    = (unsigned*)(wsb + 23101440);                //      8,064 B (63*32*4)
    unsigned short* xfh    = (unsigned short*)(wsb + 23111680);          // 33,554,432 B
    unsigned short* xfl    = (unsigned short*)(wsb + 56666112);          // 33,554,432 B
    const size_t kWsNeededFast = 90220544;                               // end of xfl

    const bool fast = (ws_size >= kWsNeededFast);

    hipLaunchKernelGGL(prep_w,  dim3(480), dim3(256), 0, stream, Wg, whi, wlo);
    hipLaunchKernelGGL(prep_wh, dim3(32),  dim3(256), 0, stream, Wh, whh, whl);
    hipLaunchKernelGGL(prep_h0f, dim3(8),  dim3(256), 0, stream, hinit, h0fh, h0fl, cnt);

    if (fast) {
        hipLaunchKernelGGL(prep_x, dim3(8192), dim3(256), 0, stream, x, xfh, xfl);
        for (int d = 0; d < kM + kN - 1; ++d) {
            const int ilo = max(0, d - (kN - 1));
            const int ihi = min(d, kM - 1);
            const int ncell = ihi - ilo + 1;
            hipLaunchKernelGGL(gate_cell, dim3(ncell * 20), dim3(256), 0, stream,
                               d, xfh, xfl, whi, wlo, hfh, hfl, h0fh, h0fl,
                               gates, bg, lns, lnb, c_bufs, out, cnt);
        }
    } else {
        for (int d = 0; d < kM + kN - 1; ++d) {
            const int ilo = max(0, d - (kN - 1));
            const int ihi = min(d, kM - 1);
            const int ncell = ihi - ilo + 1;
            hipLaunchKernelGGL(gate_mfma_legacy, dim3(ncell * 20), dim3(256), 0, stream,
                               d, x, whi, wlo, hfh, hfl, h0fh, h0fl, gates);
            hipLaunchKernelGGL(cell_ln, dim3(ncell * 16), dim3(256), 0, stream,
                               d, bg, lns, lnb, gates, c_bufs, hfh, hfl, out);
        }
    }
    hipLaunchKernelGGL(head_mfma, dim3(1024), dim3(256), 0, stream, whh, whl, bh, out);
}

// Round 6
// 1620.547 us; speedup vs baseline: 9.5229x; 3.3808x over previous
//
#include <hip/hip_runtime.h>

// Problem dims (hardcoded per reference)
constexpr int kB   = 64;    // batch
constexpr int kM   = 32;    // rows
constexpr int kN   = 32;    // cols
constexpr int kD   = 256;   // input/vocab dim
constexpr int kH   = 256;   // hidden
constexpr int kG5  = 1280;  // 5H

typedef __attribute__((ext_vector_type(8)))  short bf16x8;
typedef __attribute__((ext_vector_type(16))) float f32x16;

__device__ __forceinline__ float bu2f(unsigned short u) {
    return __uint_as_float(((unsigned)u) << 16);
}
__device__ __forceinline__ unsigned short f2bu(float f) {
    unsigned u = __float_as_uint(f);
    return (unsigned short)((u + 0x7FFF + ((u >> 16) & 1)) >> 16);   // RNE
}
__device__ __forceinline__ void split1(float a, unsigned short& hi, unsigned short& lo) {
    hi = f2bu(a);
    lo = f2bu(a - bu2f(hi));     // |residual after lo| <= 2^-18 |a|
}
__device__ __forceinline__ float sigm(float x) { return 1.f / (1.f + expf(-x)); }

// ---------------------------------------------------------------------------
// Prep 1: swizzle Wg (fp32 [768][1280]) into MFMA-B-fragment-contiguous bf16
// hi/lo panels. B-frag for v_mfma_f32_32x32x16_bf16: lane l holds
// B[k=(l>>5)*8+j][n=l&31]. 40 ntiles x 48 chunks.
// ---------------------------------------------------------------------------
__global__ void prep_w(const float* __restrict__ Wg,
                       unsigned short* __restrict__ whi,
                       unsigned short* __restrict__ wlo) {
    const int t = blockIdx.x * 256 + threadIdx.x;     // 0..122879
    const int lane = t & 63;
    const int rest = t >> 6;
    const int s = rest % 48;
    const int ntile = rest / 48;
    const int n = ntile * 32 + (lane & 31);
    const int kb = s * 16 + (lane >> 5) * 8;
    unsigned short h8[8], l8[8];
    #pragma unroll
    for (int j = 0; j < 8; ++j) {
        const float a = Wg[(size_t)(kb + j) * kG5 + n];
        split1(a, h8[j], l8[j]);
    }
    *(bf16x8*)(whi + (size_t)t * 8) = *(const bf16x8*)h8;
    *(bf16x8*)(wlo + (size_t)t * 8) = *(const bf16x8*)l8;
}

// Prep 2: W_head (fp32 [256][256]) -> B-frag bf16 hi/lo (8 ntiles x 16 chunks)
__global__ void prep_wh(const float* __restrict__ Wh,
                        unsigned short* __restrict__ whh,
                        unsigned short* __restrict__ whl) {
    const int t = blockIdx.x * 256 + threadIdx.x;     // 0..8191
    const int lane = t & 63;
    const int rest = t >> 6;                          // 0..127
    const int kc = rest & 15;
    const int nt = rest >> 4;                         // 0..7
    const int n = nt * 32 + (lane & 31);
    const int kb = kc * 16 + (lane >> 5) * 8;
    unsigned short h8[8], l8[8];
    #pragma unroll
    for (int j = 0; j < 8; ++j) {
        const float a = Wh[(size_t)(kb + j) * kD + n];
        split1(a, h8[j], l8[j]);
    }
    *(bf16x8*)(whh + (size_t)t * 8) = *(const bf16x8*)h8;
    *(bf16x8*)(whl + (size_t)t * 8) = *(const bf16x8*)l8;
}

// Prep 3: h_init -> A-frag layout [kh 0..15][lane][8]
__global__ void prep_h0f(const float* __restrict__ hinit,
                         unsigned short* __restrict__ h0fh,
                         unsigned short* __restrict__ h0fl) {
    const int idx = blockIdx.x * 256 + threadIdx.x;   // 0..1023
    const int lane = idx & 63;
    const int kh = idx >> 6;
    const int k0 = kh * 16 + (lane >> 5) * 8;
    unsigned short h8[8], l8[8];
    #pragma unroll
    for (int j = 0; j < 8; ++j) split1(hinit[k0 + j], h8[j], l8[j]);
    *(bf16x8*)(h0fh + (size_t)idx * 8) = *(const bf16x8*)h8;
    *(bf16x8*)(h0fl + (size_t)idx * 8) = *(const bf16x8*)l8;
}

// ---------------------------------------------------------------------------
// Prep 4: pre-split ALL of x into A-frag bf16 hi/lo panels.
// Per (cell,mt): [kh 0..15][lane 0..63][8].
// ---------------------------------------------------------------------------
__global__ void prep_x(const float* __restrict__ x,
                       unsigned short* __restrict__ xfh,
                       unsigned short* __restrict__ xfl) {
    const int t = blockIdx.x * 256 + threadIdx.x;     // 0..2097151
    const int kq   = t & 31;            // k/8
    const int b    = (t >> 5) & 63;
    const int cell = t >> 11;           // i*kN+j, 0..1023
    const float* src = x + (((size_t)b * 1024 + cell) * kD + kq * 8);
    unsigned short h8[8], l8[8];
    #pragma unroll
    for (int j = 0; j < 8; ++j) split1(src[j], h8[j], l8[j]);
    const int mt = b >> 5, kh = kq >> 1;
    const int l  = (b & 31) + 32 * (kq & 1);
    const size_t dst = ((((size_t)cell * 2 + mt) * 16 + kh) * 64 + l) * 8;
    *(bf16x8*)(xfh + dst) = *(const bf16x8*)h8;
    *(bf16x8*)(xfl + dst) = *(const bf16x8*)l8;
}

// ---------------------------------------------------------------------------
// Gate body (round-3 verified structure): 20 blocks/cell, wave = 1 m-tile x
// 1 n-tile, 144 MFMA, all A operands pre-swizzled. SYNCW variant inserts an
// intra-block __syncthreads() every 4 chunks: waves 0/1 (same ntile -> same W
// lines) and 0/2 (same mt -> same A lines) then issue duplicate fetches within
// an L1-resident 32KB window, so the duplicate hits L1 instead of L2.
// A/B: even diagonals use SYNCW=true, odd use false (round-5/4 lesson: no
// cross-block sync on MI355X; this is block-local only).
// ---------------------------------------------------------------------------
template<bool SYNCW>
__device__ __forceinline__
void gate_body(int d, int unit,
               const unsigned short* __restrict__ xfh,
               const unsigned short* __restrict__ xfl,
               const unsigned short* __restrict__ whi,
               const unsigned short* __restrict__ wlo,
               const unsigned short* __restrict__ hfh,
               const unsigned short* __restrict__ hfl,
               const unsigned short* __restrict__ h0fh,
               const unsigned short* __restrict__ h0fl,
               float* __restrict__ gates) {
    const int tid = threadIdx.x;
    const int ilo = max(0, d - (kN - 1));
    const int cell = unit / 20;
    const int nc   = unit % 20;
    const int i = ilo + cell;
    const int j = d - i;
    const int w = tid >> 6, lane = tid & 63;
    const int ln31 = lane & 31, ln5 = lane >> 5;
    const int mt = w & 1;                        // m-tile (batch rows mt*32..)
    const int ntile = nc * 2 + (w >> 1);         // global 32-col tile
    const int hp = (d + 1) & 1;                  // h plane written at diag d-1
    const int cl = i * kN + j;                   // linear cell index

    f32x16 acc;
    #pragma unroll
    for (int r = 0; r < 16; ++r) acc[r] = 0.f;

    const unsigned short* wph = whi + ((size_t)ntile * 3072 + lane) * 8;
    const unsigned short* wpl = wlo + ((size_t)ntile * 3072 + lane) * 8;

    // ---- x part: chunks 0..15, pre-split frags ----
    const unsigned short* xph = xfh + (((size_t)cl * 2 + mt) * 16 * 64 + lane) * 8;
    const unsigned short* xpl = xfl + (((size_t)cl * 2 + mt) * 16 * 64 + lane) * 8;
    #pragma unroll
    for (int kw = 0; kw < 4; ++kw) {
        if (SYNCW) __syncthreads();
        #pragma unroll
        for (int k4 = 0; k4 < 4; ++k4) {
            const int kh = kw * 4 + k4;
            const bf16x8 ah = *(const bf16x8*)(xph + (size_t)kh * 512);
            const bf16x8 al = *(const bf16x8*)(xpl + (size_t)kh * 512);
            const bf16x8 wh = *(const bf16x8*)(wph + (size_t)kh * 512);
            const bf16x8 wl = *(const bf16x8*)(wpl + (size_t)kh * 512);
            acc = __builtin_amdgcn_mfma_f32_32x32x16_bf16(ah, wh, acc, 0, 0, 0);
            acc = __builtin_amdgcn_mfma_f32_32x32x16_bf16(ah, wl, acc, 0, 0, 0);
            acc = __builtin_amdgcn_mfma_f32_32x32x16_bf16(al, wh, acc, 0, 0, 0);
        }
    }

    // ---- h_l part: chunks 16..31; h_u part: chunks 32..47 ----
    const unsigned short *plh, *pll, *puh, *pul;
    if (j > 0) {
        const size_t o = ((size_t)(hp * kM + i)) * 16384 + ((size_t)(mt * 16) * 64 + lane) * 8;
        plh = hfh + o; pll = hfl + o;
    } else {
        plh = h0fh + lane * 8; pll = h0fl + lane * 8;
    }
    if (i > 0) {
        const size_t o = ((size_t)(hp * kM + (i - 1))) * 16384 + ((size_t)(mt * 16) * 64 + lane) * 8;
        puh = hfh + o; pul = hfl + o;
    } else {
        puh = h0fh + lane * 8; pul = h0fl + lane * 8;
    }

    #pragma unroll
    for (int kw = 0; kw < 4; ++kw) {
        if (SYNCW) __syncthreads();
        #pragma unroll
        for (int k4 = 0; k4 < 4; ++k4) {
            const int kh = kw * 4 + k4;
            const bf16x8 ah = *(const bf16x8*)(plh + (size_t)kh * 512);
            const bf16x8 al = *(const bf16x8*)(pll + (size_t)kh * 512);
            const bf16x8 wh = *(const bf16x8*)(wph + (size_t)(16 + kh) * 512);
            const bf16x8 wl = *(const bf16x8*)(wpl + (size_t)(16 + kh) * 512);
            acc = __builtin_amdgcn_mfma_f32_32x32x16_bf16(ah, wh, acc, 0, 0, 0);
            acc = __builtin_amdgcn_mfma_f32_32x32x16_bf16(ah, wl, acc, 0, 0, 0);
            acc = __builtin_amdgcn_mfma_f32_32x32x16_bf16(al, wh, acc, 0, 0, 0);
        }
    }
    #pragma unroll
    for (int kw = 0; kw < 4; ++kw) {
        if (SYNCW) __syncthreads();
        #pragma unroll
        for (int k4 = 0; k4 < 4; ++k4) {
            const int kh = kw * 4 + k4;
            const bf16x8 ah = *(const bf16x8*)(puh + (size_t)kh * 512);
            const bf16x8 al = *(const bf16x8*)(pul + (size_t)kh * 512);
            const bf16x8 wh = *(const bf16x8*)(wph + (size_t)(32 + kh) * 512);
            const bf16x8 wl = *(const bf16x8*)(wpl + (size_t)(32 + kh) * 512);
            acc = __builtin_amdgcn_mfma_f32_32x32x16_bf16(ah, wh, acc, 0, 0, 0);
            acc = __builtin_amdgcn_mfma_f32_32x32x16_bf16(ah, wl, acc, 0, 0, 0);
            acc = __builtin_amdgcn_mfma_f32_32x32x16_bf16(al, wh, acc, 0, 0, 0);
        }
    }

    // ---- epilogue: C/D layout col=lane&31, row=(r&3)+8*(r>>2)+4*(lane>>5) ----
    const int col = ntile * 32 + ln31;
    #pragma unroll
    for (int r = 0; r < 16; ++r) {
        const int mrow = (r & 3) + 8 * (r >> 2) + 4 * ln5;
        const int bb = mt * 32 + mrow;
        gates[((size_t)i * kB + bb) * kG5 + col] = acc[r];
    }
}

__global__ __launch_bounds__(256)
void gate_fast(int d,
               const unsigned short* __restrict__ xfh,
               const unsigned short* __restrict__ xfl,
               const unsigned short* __restrict__ whi,
               const unsigned short* __restrict__ wlo,
               const unsigned short* __restrict__ hfh,
               const unsigned short* __restrict__ hfl,
               const unsigned short* __restrict__ h0fh,
               const unsigned short* __restrict__ h0fl,
               float* __restrict__ gates) {
    gate_body<false>(d, blockIdx.x, xfh, xfl, whi, wlo, hfh, hfl, h0fh, h0fl, gates);
}

__global__ __launch_bounds__(256)
void gate_sync(int d,
               const unsigned short* __restrict__ xfh,
               const unsigned short* __restrict__ xfl,
               const unsigned short* __restrict__ whi,
               const unsigned short* __restrict__ wlo,
               const unsigned short* __restrict__ hfh,
               const unsigned short* __restrict__ hfl,
               const unsigned short* __restrict__ h0fh,
               const unsigned short* __restrict__ h0fl,
               float* __restrict__ gates) {
    gate_body<true>(d, blockIdx.x, xfh, xfl, whi, wlo, hfh, hfl, h0fh, h0fl, gates);
}

// ---------------------------------------------------------------------------
// Legacy gate (fallback if ws too small): in-kernel x split, round-1 verified.
// ---------------------------------------------------------------------------
__global__ __launch_bounds__(256)
void gate_mfma_legacy(int d,
               const float* __restrict__ x,
               const unsigned short* __restrict__ whi,
               const unsigned short* __restrict__ wlo,
               const unsigned short* __restrict__ hfh,
               const unsigned short* __restrict__ hfl,
               const unsigned short* __restrict__ h0fh,
               const unsigned short* __restrict__ h0fl,
               float* __restrict__ gates) {
    const int tid = threadIdx.x;
    const int ilo = max(0, d - (kN - 1));
    const int cell = blockIdx.x / 20;
    const int nc   = blockIdx.x % 20;
    const int i = ilo + cell;
    const int j = d - i;
    const int w = tid >> 6, lane = tid & 63;
    const int ln31 = lane & 31, ln5 = lane >> 5;
    const int mt = w & 1;
    const int ntile = nc * 2 + (w >> 1);
    const int hp = (d + 1) & 1;

    f32x16 acc;
    #pragma unroll
    for (int r = 0; r < 16; ++r) acc[r] = 0.f;

    const unsigned short* wph = whi + ((size_t)ntile * 3072 + lane) * 8;
    const unsigned short* wpl = wlo + ((size_t)ntile * 3072 + lane) * 8;

    const int b = mt * 32 + ln31;
    const float* xr = x + (((size_t)b * kM + i) * kN + j) * kD + ln5 * 8;
    #pragma unroll 4
    for (int kh = 0; kh < 16; ++kh) {
        const float4 v0 = *(const float4*)(xr + kh * 16);
        const float4 v1 = *(const float4*)(xr + kh * 16 + 4);
        unsigned short h8[8], l8[8];
        split1(v0.x, h8[0], l8[0]); split1(v0.y, h8[1], l8[1]);
        split1(v0.z, h8[2], l8[2]); split1(v0.w, h8[3], l8[3]);
        split1(v1.x, h8[4], l8[4]); split1(v1.y, h8[5], l8[5]);
        split1(v1.z, h8[6], l8[6]); split1(v1.w, h8[7], l8[7]);
        const bf16x8 ah = *(const bf16x8*)h8;
        const bf16x8 al = *(const bf16x8*)l8;
        const bf16x8 wh = *(const bf16x8*)(wph + (size_t)kh * 512);
        const bf16x8 wl = *(const bf16x8*)(wpl + (size_t)kh * 512);
        acc = __builtin_amdgcn_mfma_f32_32x32x16_bf16(ah, wh, acc, 0, 0, 0);
        acc = __builtin_amdgcn_mfma_f32_32x32x16_bf16(ah, wl, acc, 0, 0, 0);
        acc = __builtin_amdgcn_mfma_f32_32x32x16_bf16(al, wh, acc, 0, 0, 0);
    }

    const unsigned short *plh, *pll, *puh, *pul;
    if (j > 0) {
        const size_t o = ((size_t)(hp * kM + i)) * 16384 + ((size_t)(mt * 16) * 64 + lane) * 8;
        plh = hfh + o; pll = hfl + o;
    } else {
        plh = h0fh + lane * 8; pll = h0fl + lane * 8;
    }
    if (i > 0) {
        const size_t o = ((size_t)(hp * kM + (i - 1))) * 16384 + ((size_t)(mt * 16) * 64 + lane) * 8;
        puh = hfh + o; pul = hfl + o;
    } else {
        puh = h0fh + lane * 8; pul = h0fl + lane * 8;
    }

    #pragma unroll 4
    for (int kh = 0; kh < 16; ++kh) {
        const bf16x8 ah = *(const bf16x8*)(plh + (size_t)kh * 512);
        const bf16x8 al = *(const bf16x8*)(pll + (size_t)kh * 512);
        const bf16x8 wh = *(const bf16x8*)(wph + (size_t)(16 + kh) * 512);
        const bf16x8 wl = *(const bf16x8*)(wpl + (size_t)(16 + kh) * 512);
        acc = __builtin_amdgcn_mfma_f32_32x32x16_bf16(ah, wh, acc, 0, 0, 0);
        acc = __builtin_amdgcn_mfma_f32_32x32x16_bf16(ah, wl, acc, 0, 0, 0);
        acc = __builtin_amdgcn_mfma_f32_32x32x16_bf16(al, wh, acc, 0, 0, 0);
    }
    #pragma unroll 4
    for (int kh = 0; kh < 16; ++kh) {
        const bf16x8 ah = *(const bf16x8*)(puh + (size_t)kh * 512);
        const bf16x8 al = *(const bf16x8*)(pul + (size_t)kh * 512);
        const bf16x8 wh = *(const bf16x8*)(wph + (size_t)(32 + kh) * 512);
        const bf16x8 wl = *(const bf16x8*)(wpl + (size_t)(32 + kh) * 512);
        acc = __builtin_amdgcn_mfma_f32_32x32x16_bf16(ah, wh, acc, 0, 0, 0);
        acc = __builtin_amdgcn_mfma_f32_32x32x16_bf16(ah, wl, acc, 0, 0, 0);
        acc = __builtin_amdgcn_mfma_f32_32x32x16_bf16(al, wh, acc, 0, 0, 0);
    }

    const int col = ntile * 32 + ln31;
    #pragma unroll
    for (int r = 0; r < 16; ++r) {
        const int mrow = (r & 3) + 8 * (r >> 2) + 4 * ln5;
        const int bb = mt * 32 + mrow;
        gates[((size_t)i * kB + bb) * kG5 + col] = acc[r];
    }
}

// ---------------------------------------------------------------------------
// Phase B (per diagonal): cell update + LayerNorm + h_new. Writes h as
// (a) A-frag bf16 hi/lo for next diagonal's gate GEMM, (b) packed hi|lo u32
// stashed into the OUTPUT buffer (in-place input for the final head GEMM).
// ---------------------------------------------------------------------------
__global__ __launch_bounds__(256)
void cell_ln(int d,
             const float* __restrict__ bg,
             const float* __restrict__ lns,
             const float* __restrict__ lnb,
             const float* __restrict__ gates,
             float* __restrict__ c_bufs,
             unsigned short* __restrict__ hfh,
             unsigned short* __restrict__ hfl,
             float* out) {
    __shared__ float red[8];
    const int tid = threadIdx.x;
    const int ilo = max(0, d - (kN - 1));
    const int i = ilo + (blockIdx.x >> 4);
    const int j = d - i;
    const int b0 = (blockIdx.x & 15) * 4;
    const int plane = kM * kB * kH;
    const float* c_prev = c_bufs + ((d + 1) & 1) * plane;
    float*       c_cur  = c_bufs + (d & 1) * plane;
    const int hp = d & 1;
    unsigned* outp = (unsigned*)out;

    const int u = tid;
    const float bg0 = bg[u];
    const float bg1 = bg[kH + u];
    const float bg2 = bg[2 * kH + u];
    const float bg3 = bg[3 * kH + u];
    const float bg4 = bg[4 * kH + u];
    const float lnsc = lns[u];
    const float lnbi = lnb[u];
    const int lane = tid & 63, wid = tid >> 6;
    const int kh = u >> 4, r = u & 15, jj = r & 7;

    for (int bl = 0; bl < 4; ++bl) {
        const int b = b0 + bl;
        const float* grow = gates + ((size_t)i * kB + b) * kG5;
        const float fc = grow[u] + bg0;
        const float fr = grow[kH + u] + bg1;
        const float ig = grow[2 * kH + u] + bg2;
        const float og = grow[3 * kH + u] + bg3;
        const float gg = grow[4 * kH + u] + bg4;
        const float cl = (j > 0) ? c_prev[((size_t)i * kB + b) * kH + u] : 0.f;
        const float cu = (i > 0) ? c_prev[((size_t)(i - 1) * kB + b) * kH + u] : 0.f;

        const float cell_v = sigm(fc) * cl + sigm(fr) * cu + sigm(ig) * tanhf(gg);
        c_cur[((size_t)i * kB + b) * kH + u] = cell_v;

        float s = cell_v, s2 = cell_v * cell_v;
        #pragma unroll
        for (int off = 32; off; off >>= 1) {
            s  += __shfl_down(s,  off, 64);
            s2 += __shfl_down(s2, off, 64);
        }
        if (lane == 0) { red[wid] = s; red[4 + wid] = s2; }
        __syncthreads();
        const float sum = red[0] + red[1] + red[2] + red[3];
        const float sq  = red[4] + red[5] + red[6] + red[7];
        __syncthreads();

        const float mu   = sum * (1.f / kH);
        const float var  = sq * (1.f / kH) - mu * mu;
        const float rstd = rsqrtf(var + 1e-6f);
        const float hv   = sigm(og) * tanhf((cell_v - mu) * rstd * lnsc + lnbi);

        unsigned short hb, lb;
        split1(hv, hb, lb);
        const int mt2 = b >> 5;
        const int fl = (b & 31) + 32 * (r >> 3);
        const size_t fo = ((size_t)(hp * kM + i)) * 16384
                        + (((size_t)(mt2 * 16 + kh) * 64 + fl) * 8 + jj);
        hfh[fo] = hb; hfl[fo] = lb;
        outp[(((size_t)b * kM + i) * kN + j) * kD + u] = (unsigned)hb | ((unsigned)lb << 16);
    }
}

// ---------------------------------------------------------------------------
// Final batched head GEMM: logits[R][:] = h[R][:] @ W_head + b_head, in-place
// over `out` (packed bf16 h -> fp32 logits). Block owns 64 rows x 256 cols.
// ---------------------------------------------------------------------------
__global__ __launch_bounds__(256)
void head_mfma(const unsigned short* __restrict__ whh,
               const unsigned short* __restrict__ whl,
               const float* __restrict__ bh,
               float* out) {
    const int tid = threadIdx.x;
    const int lane = tid & 63, w = tid >> 6;
    const int ln31 = lane & 31, ln5 = lane >> 5;
    const int r0 = blockIdx.x * 64;
    const int mt = w & 1, ng = w >> 1;
    unsigned* outp = (unsigned*)out;

    f32x16 acc[4];
    #pragma unroll
    for (int t = 0; t < 4; ++t)
        #pragma unroll
        for (int r = 0; r < 16; ++r) acc[t][r] = 0.f;

    const int m = r0 + mt * 32 + ln31;
    const unsigned* arow = outp + (size_t)m * kD + ln5 * 8;

    #pragma unroll 2
    for (int kc = 0; kc < 16; ++kc) {
        const uint4 p0 = *(const uint4*)(arow + kc * 16);
        const uint4 p1 = *(const uint4*)(arow + kc * 16 + 4);
        unsigned short h8[8], l8[8];
        h8[0] = (unsigned short)(p0.x & 0xffffu); l8[0] = (unsigned short)(p0.x >> 16);
        h8[1] = (unsigned short)(p0.y & 0xffffu); l8[1] = (unsigned short)(p0.y >> 16);
        h8[2] = (unsigned short)(p0.z & 0xffffu); l8[2] = (unsigned short)(p0.z >> 16);
        h8[3] = (unsigned short)(p0.w & 0xffffu); l8[3] = (unsigned short)(p0.w >> 16);
        h8[4] = (unsigned short)(p1.x & 0xffffu); l8[4] = (unsigned short)(p1.x >> 16);
        h8[5] = (unsigned short)(p1.y & 0xffffu); l8[5] = (unsigned short)(p1.y >> 16);
        h8[6] = (unsigned short)(p1.z & 0xffffu); l8[6] = (unsigned short)(p1.z >> 16);
        h8[7] = (unsigned short)(p1.w & 0xffffu); l8[7] = (unsigned short)(p1.w >> 16);
        const bf16x8 ah = *(const bf16x8*)h8;
        const bf16x8 al = *(const bf16x8*)l8;
        #pragma unroll
        for (int t = 0; t < 4; ++t) {
            const int nt = ng * 4 + t;
            const size_t g = ((size_t)(nt * 16 + kc) * 64 + lane) * 8;
            const bf16x8 wh = *(const bf16x8*)(whh + g);
            const bf16x8 wl = *(const bf16x8*)(whl + g);
            acc[t] = __builtin_amdgcn_mfma_f32_32x32x16_bf16(ah, wh, acc[t], 0, 0, 0);
            acc[t] = __builtin_amdgcn_mfma_f32_32x32x16_bf16(ah, wl, acc[t], 0, 0, 0);
            acc[t] = __builtin_amdgcn_mfma_f32_32x32x16_bf16(al, wh, acc[t], 0, 0, 0);
        }
    }

    __syncthreads();   // all packed-h reads done before any in-place store

    #pragma unroll
    for (int t = 0; t < 4; ++t) {
        const int col = (ng * 4 + t) * 32 + ln31;
        const float bb = bh[col];
        #pragma unroll
        for (int r = 0; r < 16; ++r) {
            const int row = r0 + mt * 32 + (r & 3) + 8 * (r >> 2) + 4 * ln5;
            out[(size_t)row * kD + col] = acc[t][r] + bb;
        }
    }
}

extern "C" void kernel_launch(void* const* d_in, const int* in_sizes, int n_in,
                              void* d_out, int out_size, void* d_ws, size_t ws_size,
                              hipStream_t stream) {
    const float* x     = (const float*)d_in[0];
    const float* Wg    = (const float*)d_in[1];
    const float* bg    = (const float*)d_in[2];
    const float* lns   = (const float*)d_in[3];
    const float* lnb   = (const float*)d_in[4];
    const float* Wh    = (const float*)d_in[5];
    const float* bh    = (const float*)d_in[6];
    const float* hinit = (const float*)d_in[7];
    float* out = (float*)d_out;

    // ws layout (byte offsets, all 16B-aligned)
    char* wsb = (char*)d_ws;
    float*          gates  = (float*)(wsb);                              // 10,485,760 B
    float*          c_bufs = (float*)(wsb + 10485760);                   //  4,194,304 B
    unsigned short* hfh    = (unsigned short*)(wsb + 14680064);          //  2,097,152 B
    unsigned short* hfl    = (unsigned short*)(wsb + 16777216);          //  2,097,152 B
    unsigned short* whi    = (unsigned short*)(wsb + 18874368);          //  1,966,080 B
    unsigned short* wlo    = (unsigned short*)(wsb + 20840448);          //  1,966,080 B
    unsigned short* h0fh   = (unsigned short*)(wsb + 22806528);          //     16,384 B
    unsigned short* h0fl   = (unsigned short*)(wsb + 22822912);          //     16,384 B
    unsigned short* whh    = (unsigned short*)(wsb + 22839296);          //    131,072 B
    unsigned short* whl    = (unsigned short*)(wsb + 22970368);          //    131,072 B
    unsigned short* xfh    = (unsigned short*)(wsb + 23101440);          // 33,554,432 B
    unsigned short* xfl    = (unsigned short*)(wsb + 56655872);          // 33,554,432 B
    const size_t kWsNeededFast = 90210304;                               // end of xfl

    const bool fast = (ws_size >= kWsNeededFast);

    hipLaunchKernelGGL(prep_w,  dim3(480), dim3(256), 0, stream, Wg, whi, wlo);
    hipLaunchKernelGGL(prep_wh, dim3(32),  dim3(256), 0, stream, Wh, whh, whl);
    hipLaunchKernelGGL(prep_h0f, dim3(4),  dim3(256), 0, stream, hinit, h0fh, h0fl);
    if (fast)
        hipLaunchKernelGGL(prep_x, dim3(8192), dim3(256), 0, stream, x, xfh, xfl);

    for (int d = 0; d < kM + kN - 1; ++d) {
        const int ilo = max(0, d - (kN - 1));
        const int ihi = min(d, kM - 1);
        const int ncell = ihi - ilo + 1;
        if (fast) {
            if (d & 1) {
                hipLaunchKernelGGL(gate_fast, dim3(ncell * 20), dim3(256), 0, stream,
                                   d, xfh, xfl, whi, wlo, hfh, hfl, h0fh, h0fl, gates);
            } else {
                hipLaunchKernelGGL(gate_sync, dim3(ncell * 20), dim3(256), 0, stream,
                                   d, xfh, xfl, whi, wlo, hfh, hfl, h0fh, h0fl, gates);
            }
        } else {
            hipLaunchKernelGGL(gate_mfma_legacy, dim3(ncell * 20), dim3(256), 0, stream,
                               d, x, whi, wlo, hfh, hfl, h0fh, h0fl, gates);
        }
        hipLaunchKernelGGL(cell_ln, dim3(ncell * 16), dim3(256), 0, stream,
                           d, bg, lns, lnb, gates, c_bufs, hfh, hfl, out);
    }
    hipLaunchKernelGGL(head_mfma, dim3(1024), dim3(256), 0, stream, whh, whl, bh, out);
}

// Round 7
// 1553.504 us; speedup vs baseline: 9.9339x; 1.0432x over previous
//
#include <hip/hip_runtime.h>

// Problem dims (hardcoded per reference)
constexpr int kB   = 64;    // batch
constexpr int kM   = 32;    // rows
constexpr int kN   = 32;    // cols
constexpr int kD   = 256;   // input/vocab dim
constexpr int kH   = 256;   // hidden
constexpr int kG5  = 1280;  // 5H

typedef __attribute__((ext_vector_type(8)))  short bf16x8;
typedef __attribute__((ext_vector_type(16))) float f32x16;

__device__ __forceinline__ float bu2f(unsigned short u) {
    return __uint_as_float(((unsigned)u) << 16);
}
__device__ __forceinline__ unsigned short f2bu(float f) {
    unsigned u = __float_as_uint(f);
    return (unsigned short)((u + 0x7FFF + ((u >> 16) & 1)) >> 16);   // RNE
}
__device__ __forceinline__ void split1(float a, unsigned short& hi, unsigned short& lo) {
    hi = f2bu(a);
    lo = f2bu(a - bu2f(hi));     // |residual after lo| <= 2^-18 |a|
}
__device__ __forceinline__ float sigm(float x) { return 1.f / (1.f + expf(-x)); }

// ---------------------------------------------------------------------------
// Prep 1: swizzle Wg (fp32 [768][1280]) into MFMA-B-fragment-contiguous bf16
// hi/lo panels. B-frag for v_mfma_f32_32x32x16_bf16: lane l holds
// B[k=(l>>5)*8+j][n=l&31]. 40 ntiles x 48 chunks.
// ---------------------------------------------------------------------------
__global__ void prep_w(const float* __restrict__ Wg,
                       unsigned short* __restrict__ whi,
                       unsigned short* __restrict__ wlo) {
    const int t = blockIdx.x * 256 + threadIdx.x;     // 0..122879
    const int lane = t & 63;
    const int rest = t >> 6;
    const int s = rest % 48;
    const int ntile = rest / 48;
    const int n = ntile * 32 + (lane & 31);
    const int kb = s * 16 + (lane >> 5) * 8;
    unsigned short h8[8], l8[8];
    #pragma unroll
    for (int j = 0; j < 8; ++j) {
        const float a = Wg[(size_t)(kb + j) * kG5 + n];
        split1(a, h8[j], l8[j]);
    }
    *(bf16x8*)(whi + (size_t)t * 8) = *(const bf16x8*)h8;
    *(bf16x8*)(wlo + (size_t)t * 8) = *(const bf16x8*)l8;
}

// Prep 2: W_head (fp32 [256][256]) -> B-frag bf16 hi/lo (8 ntiles x 16 chunks)
__global__ void prep_wh(const float* __restrict__ Wh,
                        unsigned short* __restrict__ whh,
                        unsigned short* __restrict__ whl) {
    const int t = blockIdx.x * 256 + threadIdx.x;     // 0..8191
    const int lane = t & 63;
    const int rest = t >> 6;                          // 0..127
    const int kc = rest & 15;
    const int nt = rest >> 4;                         // 0..7
    const int n = nt * 32 + (lane & 31);
    const int kb = kc * 16 + (lane >> 5) * 8;
    unsigned short h8[8], l8[8];
    #pragma unroll
    for (int j = 0; j < 8; ++j) {
        const float a = Wh[(size_t)(kb + j) * kD + n];
        split1(a, h8[j], l8[j]);
    }
    *(bf16x8*)(whh + (size_t)t * 8) = *(const bf16x8*)h8;
    *(bf16x8*)(whl + (size_t)t * 8) = *(const bf16x8*)l8;
}

// Prep 3: h_init -> A-frag layout [kh 0..15][lane][8]
__global__ void prep_h0f(const float* __restrict__ hinit,
                         unsigned short* __restrict__ h0fh,
                         unsigned short* __restrict__ h0fl) {
    const int idx = blockIdx.x * 256 + threadIdx.x;   // 0..1023
    const int lane = idx & 63;
    const int kh = idx >> 6;
    const int k0 = kh * 16 + (lane >> 5) * 8;
    unsigned short h8[8], l8[8];
    #pragma unroll
    for (int j = 0; j < 8; ++j) split1(hinit[k0 + j], h8[j], l8[j]);
    *(bf16x8*)(h0fh + (size_t)idx * 8) = *(const bf16x8*)h8;
    *(bf16x8*)(h0fl + (size_t)idx * 8) = *(const bf16x8*)l8;
}

// ---------------------------------------------------------------------------
// Prep 4: pre-split ALL of x into A-frag bf16 hi/lo panels.
// Per (cell,mt): [kh 0..15][lane 0..63][8].
// ---------------------------------------------------------------------------
__global__ void prep_x(const float* __restrict__ x,
                       unsigned short* __restrict__ xfh,
                       unsigned short* __restrict__ xfl) {
    const int t = blockIdx.x * 256 + threadIdx.x;     // 0..2097151
    const int kq   = t & 31;            // k/8
    const int b    = (t >> 5) & 63;
    const int cell = t >> 11;           // i*kN+j, 0..1023
    const float* src = x + (((size_t)b * 1024 + cell) * kD + kq * 8);
    unsigned short h8[8], l8[8];
    #pragma unroll
    for (int j = 0; j < 8; ++j) split1(src[j], h8[j], l8[j]);
    const int mt = b >> 5, kh = kq >> 1;
    const int l  = (b & 31) + 32 * (kq & 1);
    const size_t dst = ((((size_t)cell * 2 + mt) * 16 + kh) * 64 + l) * 8;
    *(bf16x8*)(xfh + dst) = *(const bf16x8*)h8;
    *(bf16x8*)(xfl + dst) = *(const bf16x8*)l8;
}

// ---------------------------------------------------------------------------
// Gate kernel (round-6 verified SYNCW variant, now on ALL diagonals):
// 20 blocks/cell, wave = 1 m-tile x 1 n-tile, 144 MFMA. Intra-block
// __syncthreads() every 4 chunks keeps the 4 waves' duplicate W/A fetches
// inside an L1-resident window (A/B in round 6: sync diagonals ~8us faster).
// ---------------------------------------------------------------------------
__global__ __launch_bounds__(256)
void gate_sync(int d,
               const unsigned short* __restrict__ xfh,
               const unsigned short* __restrict__ xfl,
               const unsigned short* __restrict__ whi,
               const unsigned short* __restrict__ wlo,
               const unsigned short* __restrict__ hfh,
               const unsigned short* __restrict__ hfl,
               const unsigned short* __restrict__ h0fh,
               const unsigned short* __restrict__ h0fl,
               float* __restrict__ gates) {
    const int tid = threadIdx.x;
    const int ilo = max(0, d - (kN - 1));
    const int cell = blockIdx.x / 20;
    const int nc   = blockIdx.x % 20;
    const int i = ilo + cell;
    const int j = d - i;
    const int w = tid >> 6, lane = tid & 63;
    const int ln31 = lane & 31, ln5 = lane >> 5;
    const int mt = w & 1;                        // m-tile (batch rows mt*32..)
    const int ntile = nc * 2 + (w >> 1);         // global 32-col tile
    const int hp = (d + 1) & 1;                  // h plane written at diag d-1
    const int cl = i * kN + j;                   // linear cell index

    f32x16 acc;
    #pragma unroll
    for (int r = 0; r < 16; ++r) acc[r] = 0.f;

    const unsigned short* wph = whi + ((size_t)ntile * 3072 + lane) * 8;
    const unsigned short* wpl = wlo + ((size_t)ntile * 3072 + lane) * 8;

    // ---- x part: chunks 0..15, pre-split frags ----
    const unsigned short* xph = xfh + (((size_t)cl * 2 + mt) * 16 * 64 + lane) * 8;
    const unsigned short* xpl = xfl + (((size_t)cl * 2 + mt) * 16 * 64 + lane) * 8;
    #pragma unroll
    for (int kw = 0; kw < 4; ++kw) {
        __syncthreads();
        #pragma unroll
        for (int k4 = 0; k4 < 4; ++k4) {
            const int kh = kw * 4 + k4;
            const bf16x8 ah = *(const bf16x8*)(xph + (size_t)kh * 512);
            const bf16x8 al = *(const bf16x8*)(xpl + (size_t)kh * 512);
            const bf16x8 wh = *(const bf16x8*)(wph + (size_t)kh * 512);
            const bf16x8 wl = *(const bf16x8*)(wpl + (size_t)kh * 512);
            acc = __builtin_amdgcn_mfma_f32_32x32x16_bf16(ah, wh, acc, 0, 0, 0);
            acc = __builtin_amdgcn_mfma_f32_32x32x16_bf16(ah, wl, acc, 0, 0, 0);
            acc = __builtin_amdgcn_mfma_f32_32x32x16_bf16(al, wh, acc, 0, 0, 0);
        }
    }

    // ---- h_l part: chunks 16..31; h_u part: chunks 32..47 ----
    const unsigned short *plh, *pll, *puh, *pul;
    if (j > 0) {
        const size_t o = ((size_t)(hp * kM + i)) * 16384 + ((size_t)(mt * 16) * 64 + lane) * 8;
        plh = hfh + o; pll = hfl + o;
    } else {
        plh = h0fh + lane * 8; pll = h0fl + lane * 8;
    }
    if (i > 0) {
        const size_t o = ((size_t)(hp * kM + (i - 1))) * 16384 + ((size_t)(mt * 16) * 64 + lane) * 8;
        puh = hfh + o; pul = hfl + o;
    } else {
        puh = h0fh + lane * 8; pul = h0fl + lane * 8;
    }

    #pragma unroll
    for (int kw = 0; kw < 4; ++kw) {
        __syncthreads();
        #pragma unroll
        for (int k4 = 0; k4 < 4; ++k4) {
            const int kh = kw * 4 + k4;
            const bf16x8 ah = *(const bf16x8*)(plh + (size_t)kh * 512);
            const bf16x8 al = *(const bf16x8*)(pll + (size_t)kh * 512);
            const bf16x8 wh = *(const bf16x8*)(wph + (size_t)(16 + kh) * 512);
            const bf16x8 wl = *(const bf16x8*)(wpl + (size_t)(16 + kh) * 512);
            acc = __builtin_amdgcn_mfma_f32_32x32x16_bf16(ah, wh, acc, 0, 0, 0);
            acc = __builtin_amdgcn_mfma_f32_32x32x16_bf16(ah, wl, acc, 0, 0, 0);
            acc = __builtin_amdgcn_mfma_f32_32x32x16_bf16(al, wh, acc, 0, 0, 0);
        }
    }
    #pragma unroll
    for (int kw = 0; kw < 4; ++kw) {
        __syncthreads();
        #pragma unroll
        for (int k4 = 0; k4 < 4; ++k4) {
            const int kh = kw * 4 + k4;
            const bf16x8 ah = *(const bf16x8*)(puh + (size_t)kh * 512);
            const bf16x8 al = *(const bf16x8*)(pul + (size_t)kh * 512);
            const bf16x8 wh = *(const bf16x8*)(wph + (size_t)(32 + kh) * 512);
            const bf16x8 wl = *(const bf16x8*)(wpl + (size_t)(32 + kh) * 512);
            acc = __builtin_amdgcn_mfma_f32_32x32x16_bf16(ah, wh, acc, 0, 0, 0);
            acc = __builtin_amdgcn_mfma_f32_32x32x16_bf16(ah, wl, acc, 0, 0, 0);
            acc = __builtin_amdgcn_mfma_f32_32x32x16_bf16(al, wh, acc, 0, 0, 0);
        }
    }

    // ---- epilogue: C/D layout col=lane&31, row=(r&3)+8*(r>>2)+4*(lane>>5) ----
    const int col = ntile * 32 + ln31;
    #pragma unroll
    for (int r = 0; r < 16; ++r) {
        const int mrow = (r & 3) + 8 * (r >> 2) + 4 * ln5;
        const int bb = mt * 32 + mrow;
        gates[((size_t)i * kB + bb) * kG5 + col] = acc[r];
    }
}

// ---------------------------------------------------------------------------
// Legacy gate (fallback if ws too small): in-kernel x split, round-1 verified.
// ---------------------------------------------------------------------------
__global__ __launch_bounds__(256)
void gate_mfma_legacy(int d,
               const float* __restrict__ x,
               const unsigned short* __restrict__ whi,
               const unsigned short* __restrict__ wlo,
               const unsigned short* __restrict__ hfh,
               const unsigned short* __restrict__ hfl,
               const unsigned short* __restrict__ h0fh,
               const unsigned short* __restrict__ h0fl,
               float* __restrict__ gates) {
    const int tid = threadIdx.x;
    const int ilo = max(0, d - (kN - 1));
    const int cell = blockIdx.x / 20;
    const int nc   = blockIdx.x % 20;
    const int i = ilo + cell;
    const int j = d - i;
    const int w = tid >> 6, lane = tid & 63;
    const int ln31 = lane & 31, ln5 = lane >> 5;
    const int mt = w & 1;
    const int ntile = nc * 2 + (w >> 1);
    const int hp = (d + 1) & 1;

    f32x16 acc;
    #pragma unroll
    for (int r = 0; r < 16; ++r) acc[r] = 0.f;

    const unsigned short* wph = whi + ((size_t)ntile * 3072 + lane) * 8;
    const unsigned short* wpl = wlo + ((size_t)ntile * 3072 + lane) * 8;

    const int b = mt * 32 + ln31;
    const float* xr = x + (((size_t)b * kM + i) * kN + j) * kD + ln5 * 8;
    #pragma unroll 4
    for (int kh = 0; kh < 16; ++kh) {
        const float4 v0 = *(const float4*)(xr + kh * 16);
        const float4 v1 = *(const float4*)(xr + kh * 16 + 4);
        unsigned short h8[8], l8[8];
        split1(v0.x, h8[0], l8[0]); split1(v0.y, h8[1], l8[1]);
        split1(v0.z, h8[2], l8[2]); split1(v0.w, h8[3], l8[3]);
        split1(v1.x, h8[4], l8[4]); split1(v1.y, h8[5], l8[5]);
        split1(v1.z, h8[6], l8[6]); split1(v1.w, h8[7], l8[7]);
        const bf16x8 ah = *(const bf16x8*)h8;
        const bf16x8 al = *(const bf16x8*)l8;
        const bf16x8 wh = *(const bf16x8*)(wph + (size_t)kh * 512);
        const bf16x8 wl = *(const bf16x8*)(wpl + (size_t)kh * 512);
        acc = __builtin_amdgcn_mfma_f32_32x32x16_bf16(ah, wh, acc, 0, 0, 0);
        acc = __builtin_amdgcn_mfma_f32_32x32x16_bf16(ah, wl, acc, 0, 0, 0);
        acc = __builtin_amdgcn_mfma_f32_32x32x16_bf16(al, wh, acc, 0, 0, 0);
    }

    const unsigned short *plh, *pll, *puh, *pul;
    if (j > 0) {
        const size_t o = ((size_t)(hp * kM + i)) * 16384 + ((size_t)(mt * 16) * 64 + lane) * 8;
        plh = hfh + o; pll = hfl + o;
    } else {
        plh = h0fh + lane * 8; pll = h0fl + lane * 8;
    }
    if (i > 0) {
        const size_t o = ((size_t)(hp * kM + (i - 1))) * 16384 + ((size_t)(mt * 16) * 64 + lane) * 8;
        puh = hfh + o; pul = hfl + o;
    } else {
        puh = h0fh + lane * 8; pul = h0fl + lane * 8;
    }

    #pragma unroll 4
    for (int kh = 0; kh < 16; ++kh) {
        const bf16x8 ah = *(const bf16x8*)(plh + (size_t)kh * 512);
        const bf16x8 al = *(const bf16x8*)(pll + (size_t)kh * 512);
        const bf16x8 wh = *(const bf16x8*)(wph + (size_t)(16 + kh) * 512);
        const bf16x8 wl = *(const bf16x8*)(wpl + (size_t)(16 + kh) * 512);
        acc = __builtin_amdgcn_mfma_f32_32x32x16_bf16(ah, wh, acc, 0, 0, 0);
        acc = __builtin_amdgcn_mfma_f32_32x32x16_bf16(ah, wl, acc, 0, 0, 0);
        acc = __builtin_amdgcn_mfma_f32_32x32x16_bf16(al, wh, acc, 0, 0, 0);
    }
    #pragma unroll 4
    for (int kh = 0; kh < 16; ++kh) {
        const bf16x8 ah = *(const bf16x8*)(puh + (size_t)kh * 512);
        const bf16x8 al = *(const bf16x8*)(pul + (size_t)kh * 512);
        const bf16x8 wh = *(const bf16x8*)(wph + (size_t)(32 + kh) * 512);
        const bf16x8 wl = *(const bf16x8*)(wpl + (size_t)(32 + kh) * 512);
        acc = __builtin_amdgcn_mfma_f32_32x32x16_bf16(ah, wh, acc, 0, 0, 0);
        acc = __builtin_amdgcn_mfma_f32_32x32x16_bf16(ah, wl, acc, 0, 0, 0);
        acc = __builtin_amdgcn_mfma_f32_32x32x16_bf16(al, wh, acc, 0, 0, 0);
    }

    const int col = ntile * 32 + ln31;
    #pragma unroll
    for (int r = 0; r < 16; ++r) {
        const int mrow = (r & 3) + 8 * (r >> 2) + 4 * ln5;
        const int bb = mt * 32 + mrow;
        gates[((size_t)i * kB + bb) * kG5 + col] = acc[r];
    }
}

// ---------------------------------------------------------------------------
// Phase B (per diagonal): cell update + LayerNorm + h_new. Writes h as
// (a) A-frag bf16 hi/lo for next diagonal's gate GEMM, (b) packed hi|lo u32
// stashed into the OUTPUT buffer (in-place input for the final head GEMM).
// ---------------------------------------------------------------------------
__global__ __launch_bounds__(256)
void cell_ln(int d,
             const float* __restrict__ bg,
             const float* __restrict__ lns,
             const float* __restrict__ lnb,
             const float* __restrict__ gates,
             float* __restrict__ c_bufs,
             unsigned short* __restrict__ hfh,
             unsigned short* __restrict__ hfl,
             float* out) {
    __shared__ float red[8];
    const int tid = threadIdx.x;
    const int ilo = max(0, d - (kN - 1));
    const int i = ilo + (blockIdx.x >> 4);
    const int j = d - i;
    const int b0 = (blockIdx.x & 15) * 4;
    const int plane = kM * kB * kH;
    const float* c_prev = c_bufs + ((d + 1) & 1) * plane;
    float*       c_cur  = c_bufs + (d & 1) * plane;
    const int hp = d & 1;
    unsigned* outp = (unsigned*)out;

    const int u = tid;
    const float bg0 = bg[u];
    const float bg1 = bg[kH + u];
    const float bg2 = bg[2 * kH + u];
    const float bg3 = bg[3 * kH + u];
    const float bg4 = bg[4 * kH + u];
    const float lnsc = lns[u];
    const float lnbi = lnb[u];
    const int lane = tid & 63, wid = tid >> 6;
    const int kh = u >> 4, r = u & 15, jj = r & 7;

    for (int bl = 0; bl < 4; ++bl) {
        const int b = b0 + bl;
        const float* grow = gates + ((size_t)i * kB + b) * kG5;
        const float fc = grow[u] + bg0;
        const float fr = grow[kH + u] + bg1;
        const float ig = grow[2 * kH + u] + bg2;
        const float og = grow[3 * kH + u] + bg3;
        const float gg = grow[4 * kH + u] + bg4;
        const float cl = (j > 0) ? c_prev[((size_t)i * kB + b) * kH + u] : 0.f;
        const float cu = (i > 0) ? c_prev[((size_t)(i - 1) * kB + b) * kH + u] : 0.f;

        const float cell_v = sigm(fc) * cl + sigm(fr) * cu + sigm(ig) * tanhf(gg);
        c_cur[((size_t)i * kB + b) * kH + u] = cell_v;

        float s = cell_v, s2 = cell_v * cell_v;
        #pragma unroll
        for (int off = 32; off; off >>= 1) {
            s  += __shfl_down(s,  off, 64);
            s2 += __shfl_down(s2, off, 64);
        }
        if (lane == 0) { red[wid] = s; red[4 + wid] = s2; }
        __syncthreads();
        const float sum = red[0] + red[1] + red[2] + red[3];
        const float sq  = red[4] + red[5] + red[6] + red[7];
        __syncthreads();

        const float mu   = sum * (1.f / kH);
        const float var  = sq * (1.f / kH) - mu * mu;
        const float rstd = rsqrtf(var + 1e-6f);
        const float hv   = sigm(og) * tanhf((cell_v - mu) * rstd * lnsc + lnbi);

        unsigned short hb, lb;
        split1(hv, hb, lb);
        const int mt2 = b >> 5;
        const int fl = (b & 31) + 32 * (r >> 3);
        const size_t fo = ((size_t)(hp * kM + i)) * 16384
                        + (((size_t)(mt2 * 16 + kh) * 64 + fl) * 8 + jj);
        hfh[fo] = hb; hfl[fo] = lb;
        outp[(((size_t)b * kM + i) * kN + j) * kD + u] = (unsigned)hb | ((unsigned)lb << 16);
    }
}

// ---------------------------------------------------------------------------
// Final batched head GEMM, 128 rows/block (512 blocks): halves the per-grid
// W-panel L2 traffic vs 64 rows/block (536 MB -> 268 MB) via in-register W
// reuse across two row-halves. In-place over `out`: block reads only its own
// 128 rows (packed bf16), __syncthreads(), writes only its own rows.
// Wave w: mt = w&1 (rows +mt*32, both halves), ng = w>>1 (ntiles ng*4..+3).
// ---------------------------------------------------------------------------
__global__ __launch_bounds__(256)
void head_mfma(const unsigned short* __restrict__ whh,
               const unsigned short* __restrict__ whl,
               const float* __restrict__ bh,
               float* out) {
    const int tid = threadIdx.x;
    const int lane = tid & 63, w = tid >> 6;
    const int ln31 = lane & 31, ln5 = lane >> 5;
    const int r0 = blockIdx.x * 128;
    const int mt = w & 1, ng = w >> 1;
    unsigned* outp = (unsigned*)out;

    f32x16 acc[2][4];
    #pragma unroll
    for (int h = 0; h < 2; ++h)
        #pragma unroll
        for (int t = 0; t < 4; ++t)
            #pragma unroll
            for (int r = 0; r < 16; ++r) acc[h][t][r] = 0.f;

    const unsigned* arow0 = outp + (size_t)(r0 + mt * 32 + ln31) * kD + ln5 * 8;
    const unsigned* arow1 = arow0 + (size_t)64 * kD;

    #pragma unroll 2
    for (int kc = 0; kc < 16; ++kc) {
        unsigned short h8a[8], l8a[8], h8b[8], l8b[8];
        {
            const uint4 p0 = *(const uint4*)(arow0 + kc * 16);
            const uint4 p1 = *(const uint4*)(arow0 + kc * 16 + 4);
            h8a[0] = (unsigned short)(p0.x & 0xffffu); l8a[0] = (unsigned short)(p0.x >> 16);
            h8a[1] = (unsigned short)(p0.y & 0xffffu); l8a[1] = (unsigned short)(p0.y >> 16);
            h8a[2] = (unsigned short)(p0.z & 0xffffu); l8a[2] = (unsigned short)(p0.z >> 16);
            h8a[3] = (unsigned short)(p0.w & 0xffffu); l8a[3] = (unsigned short)(p0.w >> 16);
            h8a[4] = (unsigned short)(p1.x & 0xffffu); l8a[4] = (unsigned short)(p1.x >> 16);
            h8a[5] = (unsigned short)(p1.y & 0xffffu); l8a[5] = (unsigned short)(p1.y >> 16);
            h8a[6] = (unsigned short)(p1.z & 0xffffu); l8a[6] = (unsigned short)(p1.z >> 16);
            h8a[7] = (unsigned short)(p1.w & 0xffffu); l8a[7] = (unsigned short)(p1.w >> 16);
        }
        {
            const uint4 p0 = *(const uint4*)(arow1 + kc * 16);
            const uint4 p1 = *(const uint4*)(arow1 + kc * 16 + 4);
            h8b[0] = (unsigned short)(p0.x & 0xffffu); l8b[0] = (unsigned short)(p0.x >> 16);
            h8b[1] = (unsigned short)(p0.y & 0xffffu); l8b[1] = (unsigned short)(p0.y >> 16);
            h8b[2] = (unsigned short)(p0.z & 0xffffu); l8b[2] = (unsigned short)(p0.z >> 16);
            h8b[3] = (unsigned short)(p0.w & 0xffffu); l8b[3] = (unsigned short)(p0.w >> 16);
            h8b[4] = (unsigned short)(p1.x & 0xffffu); l8b[4] = (unsigned short)(p1.x >> 16);
            h8b[5] = (unsigned short)(p1.y & 0xffffu); l8b[5] = (unsigned short)(p1.y >> 16);
            h8b[6] = (unsigned short)(p1.z & 0xffffu); l8b[6] = (unsigned short)(p1.z >> 16);
            h8b[7] = (unsigned short)(p1.w & 0xffffu); l8b[7] = (unsigned short)(p1.w >> 16);
        }
        const bf16x8 ah0 = *(const bf16x8*)h8a;
        const bf16x8 al0 = *(const bf16x8*)l8a;
        const bf16x8 ah1 = *(const bf16x8*)h8b;
        const bf16x8 al1 = *(const bf16x8*)l8b;
        #pragma unroll
        for (int t = 0; t < 4; ++t) {
            const int nt = ng * 4 + t;
            const size_t g = ((size_t)(nt * 16 + kc) * 64 + lane) * 8;
            const bf16x8 wh = *(const bf16x8*)(whh + g);
            const bf16x8 wl = *(const bf16x8*)(whl + g);
            acc[0][t] = __builtin_amdgcn_mfma_f32_32x32x16_bf16(ah0, wh, acc[0][t], 0, 0, 0);
            acc[0][t] = __builtin_amdgcn_mfma_f32_32x32x16_bf16(ah0, wl, acc[0][t], 0, 0, 0);
            acc[0][t] = __builtin_amdgcn_mfma_f32_32x32x16_bf16(al0, wh, acc[0][t], 0, 0, 0);
            acc[1][t] = __builtin_amdgcn_mfma_f32_32x32x16_bf16(ah1, wh, acc[1][t], 0, 0, 0);
            acc[1][t] = __builtin_amdgcn_mfma_f32_32x32x16_bf16(ah1, wl, acc[1][t], 0, 0, 0);
            acc[1][t] = __builtin_amdgcn_mfma_f32_32x32x16_bf16(al1, wh, acc[1][t], 0, 0, 0);
        }
    }

    __syncthreads();   // all packed-h reads done before any in-place store

    #pragma unroll
    for (int h = 0; h < 2; ++h)
        #pragma unroll
        for (int t = 0; t < 4; ++t) {
            const int col = (ng * 4 + t) * 32 + ln31;
            const float bb = bh[col];
            #pragma unroll
            for (int r = 0; r < 16; ++r) {
                const int row = r0 + h * 64 + mt * 32 + (r & 3) + 8 * (r >> 2) + 4 * ln5;
                out[(size_t)row * kD + col] = acc[h][t][r] + bb;
            }
        }
}

extern "C" void kernel_launch(void* const* d_in, const int* in_sizes, int n_in,
                              void* d_out, int out_size, void* d_ws, size_t ws_size,
                              hipStream_t stream) {
    const float* x     = (const float*)d_in[0];
    const float* Wg    = (const float*)d_in[1];
    const float* bg    = (const float*)d_in[2];
    const float* lns   = (const float*)d_in[3];
    const float* lnb   = (const float*)d_in[4];
    const float* Wh    = (const float*)d_in[5];
    const float* bh    = (const float*)d_in[6];
    const float* hinit = (const float*)d_in[7];
    float* out = (float*)d_out;

    // ws layout (byte offsets, all 16B-aligned)
    char* wsb = (char*)d_ws;
    float*          gates  = (float*)(wsb);                              // 10,485,760 B
    float*          c_bufs = (float*)(wsb + 10485760);                   //  4,194,304 B
    unsigned short* hfh    = (unsigned short*)(wsb + 14680064);          //  2,097,152 B
    unsigned short* hfl    = (unsigned short*)(wsb + 16777216);          //  2,097,152 B
    unsigned short* whi    = (unsigned short*)(wsb + 18874368);          //  1,966,080 B
    unsigned short* wlo    = (unsigned short*)(wsb + 20840448);          //  1,966,080 B
    unsigned short* h0fh   = (unsigned short*)(wsb + 22806528);          //     16,384 B
    unsigned short* h0fl   = (unsigned short*)(wsb + 22822912);          //     16,384 B
    unsigned short* whh    = (unsigned short*)(wsb + 22839296);          //    131,072 B
    unsigned short* whl    = (unsigned short*)(wsb + 22970368);          //    131,072 B
    unsigned short* xfh    = (unsigned short*)(wsb + 23101440);          // 33,554,432 B
    unsigned short* xfl    = (unsigned short*)(wsb + 56655872);          // 33,554,432 B
    const size_t kWsNeededFast = 90210304;                               // end of xfl

    const bool fast = (ws_size >= kWsNeededFast);

    hipLaunchKernelGGL(prep_w,  dim3(480), dim3(256), 0, stream, Wg, whi, wlo);
    hipLaunchKernelGGL(prep_wh, dim3(32),  dim3(256), 0, stream, Wh, whh, whl);
    hipLaunchKernelGGL(prep_h0f, dim3(4),  dim3(256), 0, stream, hinit, h0fh, h0fl);
    if (fast)
        hipLaunchKernelGGL(prep_x, dim3(8192), dim3(256), 0, stream, x, xfh, xfl);

    for (int d = 0; d < kM + kN - 1; ++d) {
        const int ilo = max(0, d - (kN - 1));
        const int ihi = min(d, kM - 1);
        const int ncell = ihi - ilo + 1;
        if (fast) {
            hipLaunchKernelGGL(gate_sync, dim3(ncell * 20), dim3(256), 0, stream,
                               d, xfh, xfl, whi, wlo, hfh, hfl, h0fh, h0fl, gates);
        } else {
            hipLaunchKernelGGL(gate_mfma_legacy, dim3(ncell * 20), dim3(256), 0, stream,
                               d, x, whi, wlo, hfh, hfl, h0fh, h0fl, gates);
        }
        hipLaunchKernelGGL(cell_ln, dim3(ncell * 16), dim3(256), 0, stream,
                           d, bg, lns, lnb, gates, c_bufs, hfh, hfl, out);
    }
    hipLaunchKernelGGL(head_mfma, dim3(512), dim3(256), 0, stream, whh, whl, bh, out);
}